// Round 7
// baseline (2348.545 us; speedup 1.0000x reference)
//
#include <hip/hip_runtime.h>
#include <math.h>

#define DEV __device__ __forceinline__

constexpr int NBLK = 512;

// ---------------- graph constants ----------------
constexpr int ESRC[36] = {0,1,2,3,4,5,6,7,8,9,10,11,12,13,14,15,16,17,18,1,2,3,4,5,6,7,8,9,10,11,12,13,14,15,16,17};
constexpr int EDST[36] = {1,2,3,4,5,6,7,8,9,10,11,12,13,14,15,16,17,18,17,0,1,2,3,4,5,6,7,8,9,10,11,12,13,14,15,16};
constexpr int SSRC[55] = {0,1,2,3,4,5,6,7,8,9,10,11,12,13,14,15,16,17,18,1,2,3,4,5,6,7,8,9,10,11,12,13,14,15,16,17,
                          0,1,2,3,4,5,6,7,8,9,10,11,12,13,14,15,16,17,18};
constexpr int SDST[55] = {1,2,3,4,5,6,7,8,9,10,11,12,13,14,15,16,17,18,17,0,1,2,3,4,5,6,7,8,9,10,11,12,13,14,15,16,
                          0,1,2,3,4,5,6,7,8,9,10,11,12,13,14,15,16,17,18};
constexpr float DINV[19] = {0.5773502691896258f,0.5f,0.5f,0.5f,0.5f,0.5f,0.5f,0.5f,0.5f,0.5f,
                            0.5f,0.5f,0.5f,0.5f,0.5f,0.5f,0.5f,0.5f,0.5773502691896258f};

// ---------------- workspace layout (float offsets) ----------------
constexpr int WS_PH  = 0;        // 4*19*1000 gat hh partials (aliases dead C1)
constexpr int WS_C1  = 0;        // 32*63*63 = 127008 (dead after S2)
constexpr int WS_C2  = 127008;   // 32*30*30 = 28800
constexpr int WS_V   = 155808;   // 6272
constexpr int WS_FC0 = 162080;   // 6000 (fc0 partial q0; NO bias)
constexpr int WS_N1  = 168080;   // 100
constexpr int WS_N2  = 168180;   // 100
constexpr int WS_HA  = 168280;   // 19*1000
constexpr int WS_HB  = 187280;   // 19*1000
constexpr int WS_AGA = 206280;   // 19*1000 (dead after S2)
constexpr int WS_FC0B= 206280;   // 6000 (fc0 partial q1; aliases AGA)
constexpr int WS_BAR = 263280;   // 16 uints barrier counters (zeroed each launch)
constexpr int WS_PB  = 264384;   // 76000 partials ping
constexpr int WS_PC  = 340384;   // 76000 partials pong (end 416384)
constexpr int WS_FC0C= 416384;   // 6000 (fc0 partial q2)
constexpr int WS_FC0D= 422384;   // 6000 (fc0 partial q3)

DEV float wredsum(float v){
  #pragma unroll
  for (int o = 32; o; o >>= 1) v += __shfl_xor(v, o);
  return v;
}
DEV float d4(float4 a, float4 b){ return a.x*b.x + a.y*b.y + a.z*b.z + a.w*b.w; }

// ---- manual grid barrier (all NBLK blocks co-resident by construction) ----
DEV void gridbar(unsigned* bar, int idx){
  __syncthreads();
  if (threadIdx.x == 0){
    __threadfence();
    __hip_atomic_fetch_add(&bar[idx], 1u, __ATOMIC_RELEASE, __HIP_MEMORY_SCOPE_AGENT);
    long guard = 0;
    while (__hip_atomic_load(&bar[idx], __ATOMIC_ACQUIRE, __HIP_MEMORY_SCOPE_AGENT) < (unsigned)NBLK){
      if (++guard > (1L<<31)) break;   // bounded: never hang the harness
      __builtin_amdgcn_s_sleep(1);
    }
    __threadfence();
  }
  __syncthreads();
}

// ============================================================================
// SAGE split matmul task (identical math to R5)
// ============================================================================
template<int MODE>
DEV void sage_split(int blk, int tid, float* sm,
                    const float* hin, const float* pin,
                    const float* pbias, const float* agin,
                    const float* lw, const float* rw, float* pout)
{
  const int cg_ = blk >> 2, kq = blk & 3;
  const int kb = kq*256;
  const int cntf = (kq < 3) ? 256 : 232;
  const int cnt4 = cntf >> 2;
  float* hS = sm;            // [19][256]
  float* aS = sm + 19*256;   // [19][256]
  if (MODE == 2){
    for (int c = tid; c < 19*256; c += 256){
      const int n = c >> 8, j = c & 255;
      if (j < cntf){
        const int i = kb + j;
        const float v = pin[n*1000+i] + pin[(19+n)*1000+i] + pin[(38+n)*1000+i]
                      + pin[(57+n)*1000+i] + pbias[i];
        hS[c] = fmaxf(v, 0.f);
      }
    }
  } else {
    for (int c = tid; c < 19*64; c += 256){
      const int n = c >> 6, j = c & 63;
      if (j < cnt4)
        ((float4*)hS)[n*64 + j] = *(const float4*)(hin + n*1000 + kb + 4*j);
    }
  }
  if (MODE == 0){
    for (int c = tid; c < 19*64; c += 256){
      const int n = c >> 6, j = c & 63;
      if (j < cnt4)
        ((float4*)aS)[n*64 + j] = *(const float4*)(agin + n*1000 + kb + 4*j);
    }
  }
  __syncthreads();
  if (MODE != 0){
    if (tid < cntf){
      float hv[19];
      #pragma unroll
      for (int n=0;n<19;++n) hv[n] = hS[n*256 + tid];
      float ag[19];
      #pragma unroll
      for (int n=0;n<19;++n) ag[n] = 0.f;
      #pragma unroll
      for (int e=0;e<36;++e) ag[EDST[e]] += hv[ESRC[e]];
      #pragma unroll
      for (int n=0;n<19;++n) aS[n*256 + tid] = ag[n];
    }
    __syncthreads();
  }
  const int lane = tid & 63, wv = tid >> 6;
  const int i0 = cg_*8 + 2*wv, i1 = i0 + 1;
  float acc0[19], acc1[19];
  #pragma unroll
  for (int n=0;n<19;++n){ acc0[n]=0.f; acc1[n]=0.f; }
  if (lane < cnt4){
    const float4 wl0 = *((const float4*)(lw + i0*1000) + kq*64 + lane);
    const float4 wl1 = *((const float4*)(lw + i1*1000) + kq*64 + lane);
    const float4 wr0 = *((const float4*)(rw + i0*1000) + kq*64 + lane);
    const float4 wr1 = *((const float4*)(rw + i1*1000) + kq*64 + lane);
    const float4* h4 = (const float4*)hS;
    const float4* a4 = (const float4*)aS;
    #pragma unroll
    for (int n=0;n<19;++n){
      const float4 hv = h4[n*64+lane], av = a4[n*64+lane];
      acc0[n] = d4(wl0,av) + d4(wr0,hv);
      acc1[n] = d4(wl1,av) + d4(wr1,hv);
    }
  }
  #pragma unroll
  for (int n=0;n<19;++n){ acc0[n]=wredsum(acc0[n]); acc1[n]=wredsum(acc1[n]); }
  if (lane == 0){
    #pragma unroll
    for (int n=0;n<19;++n){
      pout[(kq*19+n)*1000 + i0] = acc0[n];
      pout[(kq*19+n)*1000 + i1] = acc1[n];
    }
  }
}

// ============================================================================
// GAT/GCN split matmul task (identical math to R5)
// ============================================================================
template<int MODE>
DEV void gatmat_split(int blk, int tid, float* sm,
                      const float* hin, const float* pin, const float* pbias,
                      const float* W, float* pout)
{
  const int cg_ = blk >> 2, kq = blk & 3;
  const int kb = kq*256;
  const int cntf = (kq < 3) ? 256 : 232;
  const int cnt4 = cntf >> 2;
  float* hS = sm;
  if (MODE == 2){
    for (int c = tid; c < 19*256; c += 256){
      const int n = c >> 8, j = c & 255;
      if (j < cntf){
        const int i = kb + j;
        const float v = pin[n*1000+i] + pin[(19+n)*1000+i] + pin[(38+n)*1000+i]
                      + pin[(57+n)*1000+i] + pbias[i];
        hS[c] = fmaxf(v, 0.f);
      }
    }
  } else {
    for (int c = tid; c < 19*64; c += 256){
      const int n = c >> 6, j = c & 63;
      if (j < cnt4)
        ((float4*)hS)[n*64 + j] = *(const float4*)(hin + n*1000 + kb + 4*j);
    }
  }
  __syncthreads();
  const int lane = tid & 63, wv = tid >> 6;
  const int i0 = cg_*8 + 2*wv, i1 = i0 + 1;
  float acc0[19], acc1[19];
  #pragma unroll
  for (int n=0;n<19;++n){ acc0[n]=0.f; acc1[n]=0.f; }
  if (lane < cnt4){
    const float4 w0 = *((const float4*)(W + i0*1000) + kq*64 + lane);
    const float4 w1 = *((const float4*)(W + i1*1000) + kq*64 + lane);
    const float4* h4 = (const float4*)hS;
    #pragma unroll
    for (int n=0;n<19;++n){
      const float4 hv = h4[n*64+lane];
      acc0[n] = d4(w0,hv);
      acc1[n] = d4(w1,hv);
    }
  }
  #pragma unroll
  for (int n=0;n<19;++n){ acc0[n]=wredsum(acc0[n]); acc1[n]=wredsum(acc1[n]); }
  if (lane == 0){
    #pragma unroll
    for (int n=0;n<19;++n){
      pout[(kq*19+n)*1000 + i0] = acc0[n];
      pout[(kq*19+n)*1000 + i1] = acc1[n];
    }
  }
}

// ---- alpha into sm[320..374] (redundant per calling block, deterministic) ----
DEV void alpha_sm(int t, float* sm, const float* ph, const float* as_,
                  const float* ad_)
{
  const int lane = t & 63, wv = t >> 6;
  float es[19], ed[19];
  #pragma unroll
  for (int n=0;n<19;++n){ es[n]=0.f; ed[n]=0.f; }
  for (int k = t; k < 1000; k += 256){
    const float asv = as_[k], adv = ad_[k];
    #pragma unroll
    for (int n=0;n<19;++n){
      const float hh = ph[n*1000+k] + ph[(19+n)*1000+k] + ph[(38+n)*1000+k] + ph[(57+n)*1000+k];
      es[n] += hh*asv; ed[n] += hh*adv;
    }
  }
  #pragma unroll
  for (int n=0;n<19;++n){ es[n]=wredsum(es[n]); ed[n]=wredsum(ed[n]); }
  if (lane == 0){
    #pragma unroll
    for (int n=0;n<19;++n){ sm[wv*38+n]=es[n]; sm[wv*38+19+n]=ed[n]; }
  }
  __syncthreads();
  if (t < 38) sm[152+t] = sm[t] + sm[38+t] + sm[76+t] + sm[114+t]; // es:152 ed:171
  __syncthreads();
  if (t < 55){
    float e = sm[152+SSRC[t]] + sm[171+SDST[t]];
    sm[200+t] = e > 0.f ? e : 0.2f*e;
  }
  __syncthreads();
  if (t < 19){
    float m = -1e30f;
    #pragma unroll
    for (int e=0;e<55;++e) if (SDST[e]==t) m = fmaxf(m, sm[200+e]);
    float den = 0.f;
    #pragma unroll
    for (int e=0;e<55;++e) if (SDST[e]==t) den += expf(sm[200+e]-m);
    sm[260+t]=m; sm[280+t]=den;
  }
  __syncthreads();
  if (t < 55) sm[320+t] = expf(sm[200+t]-sm[260+SDST[t]]) / sm[280+SDST[t]];
  __syncthreads();
}

// ---- gat finisher task: redundant alpha + per-column aggregation chunk ----
DEV void gat_fin_task(int blk, int t, float* sm, const float* ph,
                      const float* as_, const float* ad_,
                      const float* bias, float* hout)
{
  alpha_sm(t, sm, ph, as_, ad_);
  const int i = blk*256 + t;
  if (i < 1000){
    float hv[19];
    #pragma unroll
    for (int n=0;n<19;++n)
      hv[n] = ph[n*1000+i] + ph[(19+n)*1000+i] + ph[(38+n)*1000+i] + ph[(57+n)*1000+i];
    float acc[19];
    #pragma unroll
    for (int n=0;n<19;++n) acc[n]=0.f;
    #pragma unroll
    for (int e=0;e<55;++e) acc[SDST[e]] += sm[320+e]*hv[SSRC[e]];
    const float bi = bias[i];
    #pragma unroll
    for (int n=0;n<19;++n) hout[n*1000+i] = fmaxf(acc[n]+bi, 0.f);
  }
}

// ---- conv tasks (identical math to R5) ----
DEV void conv1_task(int task, int t, const float* x, const float* c1w,
                    const float* c1b, float* ws)
{
  const int idx = task*256 + t;
  if (idx < 127008){
    const int oc = idx/3969, r = idx - oc*3969, oy = r/63, ox = r - oy*63;
    const float* wp = c1w + oc*25;
    float acc = c1b[oc];
    #pragma unroll
    for (int ky=0;ky<5;++ky){
      const int iy = oy*2 - 1 + ky;
      if ((unsigned)iy < 128u){
        #pragma unroll
        for (int kx=0;kx<5;++kx){
          const int ix = ox*2 - 1 + kx;
          if ((unsigned)ix < 128u) acc += x[iy*128+ix]*wp[ky*5+kx];
        }
      }
    }
    ws[WS_C1+idx] = fmaxf(acc, 0.f);
  }
}

DEV void conv2_task(int task, int t, float* sm, const float* c2w,
                    const float* c2b, float* ws)
{
  const int oc = task >> 2, q = task & 3;
  const int r0 = q*16;
  const int nout = (q < 3) ? 240 : 180;
  float* buf0 = sm; float* buf1 = sm + 4788;
  float rv[19];
  #pragma unroll
  for (int u=0; u<19; ++u){
    const int c = t + u*256; float v = 0.f;
    if (c < 4788){
      const int p = c/1197, r = c - p*1197, lr = r/63, xx = r - lr*63;
      const int iy = r0 + lr;
      if (iy < 63) v = ws[WS_C1 + p*3969 + iy*63 + xx];
    }
    rv[u] = v;
  }
  #pragma unroll
  for (int u=0; u<19; ++u){ const int c = t+u*256; if (c<4788) buf0[c]=rv[u]; }
  __syncthreads();
  const int oy_l = t/30, ox = t - oy_l*30;
  float acc = (t < nout) ? c2b[oc] : 0.f;
  for (int g=0; g<8; ++g){
    float* cur = (g&1) ? buf1 : buf0;
    if (g < 7){
      #pragma unroll
      for (int u=0; u<19; ++u){
        const int c = t + u*256; float v = 0.f;
        if (c < 4788){
          const int p = c/1197, r = c - p*1197, lr = r/63, xx = r - lr*63;
          const int iy = r0 + lr;
          if (iy < 63) v = ws[WS_C1 + (4*(g+1)+p)*3969 + iy*63 + xx];
        }
        rv[u] = v;
      }
    }
    if (t < nout){
      #pragma unroll
      for (int p=0;p<4;++p){
        const float* wp = c2w + (oc*32 + 4*g + p)*25;
        const float* ip = cur + p*1197 + (2*oy_l)*63 + 2*ox;
        #pragma unroll
        for (int ky=0;ky<5;++ky)
          #pragma unroll
          for (int kx=0;kx<5;++kx)
            acc += ip[ky*63+kx]*wp[ky*5+kx];
      }
    }
    if (g < 7){
      __syncthreads();
      float* nxt = (g&1) ? buf0 : buf1;
      #pragma unroll
      for (int u=0; u<19; ++u){ const int c = t+u*256; if (c<4788) nxt[c]=rv[u]; }
      __syncthreads();
    }
  }
  if (t < nout){
    const int oy = q*8 + oy_l;
    ws[WS_C2 + oc*900 + oy*30 + ox] = fmaxf(acc, 0.f);
  }
}

DEV void conv3_task(int oc, int t, float* sm, const float* c3w,
                    const float* c3b, float* ws)
{
  float* buf0 = sm; float* buf1 = sm + 3600;
  float rv[15];
  #pragma unroll
  for (int u=0; u<15; ++u){
    const int c = t + u*256;
    rv[u] = (c < 3600) ? ws[WS_C2 + c] : 0.f;
  }
  #pragma unroll
  for (int u=0; u<15; ++u){ const int c = t+u*256; if (c<3600) buf0[c]=rv[u]; }
  __syncthreads();
  const int oy = t/14, ox = t - oy*14;
  float acc = (t < 196) ? c3b[oc] : 0.f;
  for (int g=0; g<8; ++g){
    float* cur = (g&1) ? buf1 : buf0;
    if (g < 7){
      #pragma unroll
      for (int u=0; u<15; ++u){
        const int c = t + u*256;
        rv[u] = (c < 3600) ? ws[WS_C2 + (g+1)*3600 + c] : 0.f;
      }
    }
    if (t < 196){
      #pragma unroll
      for (int p=0;p<4;++p){
        const float* wp = c3w + (oc*32 + 4*g + p)*25;
        const float* ip = cur + p*900;
        #pragma unroll
        for (int ky=0;ky<5;++ky){
          const int iy = oy*2 - 1 + ky;
          if ((unsigned)iy < 30u){
            #pragma unroll
            for (int kx=0;kx<5;++kx){
              const int ix = ox*2 - 1 + kx;
              if ((unsigned)ix < 30u) acc += ip[iy*30+ix]*wp[ky*5+kx];
            }
          }
        }
      }
    }
    if (g < 7){
      __syncthreads();
      float* nxt = (g&1) ? buf0 : buf1;
      #pragma unroll
      for (int u=0; u<15; ++u){ const int c = t+u*256; if (c<3600) nxt[c]=rv[u]; }
      __syncthreads();
    }
  }
  if (t < 196) ws[WS_V + oc*196 + t] = acc;  // no relu on conv3
}

// ---- fc0 task: (rq,q) quarter-row block of 4 rows, LDS-free, reg-batched ----
DEV void fc0_task(int task, int t, const float* fc0w, float* ws)
{
  const int lane = t & 63, wv = t >> 6;
  const int rq = task >> 2, q = task & 3;
  const int row = rq*4 + wv;
  const float4* vr = (const float4*)(ws + WS_V) + q*392;
  const float4* wr = (const float4*)(fc0w) + (size_t)row*1568 + q*392;
  float4 wreg[6];
  #pragma unroll
  for (int u=0; u<6; ++u) wreg[u] = wr[u*64 + lane];
  float4 wtail;
  if (lane < 8) wtail = wr[384 + lane];
  float acc = 0.f;
  #pragma unroll
  for (int u=0; u<6; ++u) acc += d4(wreg[u], vr[u*64 + lane]);
  if (lane < 8) acc += d4(wtail, vr[384 + lane]);
  acc = wredsum(acc);
  if (lane == 0){
    float* pout = ws + (q==0 ? WS_FC0 : q==1 ? WS_FC0B : q==2 ? WS_FC0C : WS_FC0D);
    pout[row] = acc;   // bias added in fc1 consumer
  }
}

// ---- fc1 task: one row, sums 4 fc0 partials + fc0 bias inline ----
DEV void fc1_task(int row, int t, float* sm, const float* fc1w, const float* fc1b,
                  const float* fc0b, float* ws)
{
  const int lane = t & 63, wv = t >> 6;
  const float4* wr = (const float4*)(fc1w + row*6000);
  const float4* p0 = (const float4*)(ws + WS_FC0);
  const float4* p1 = (const float4*)(ws + WS_FC0B);
  const float4* p2 = (const float4*)(ws + WS_FC0C);
  const float4* p3 = (const float4*)(ws + WS_FC0D);
  const float4* bb = (const float4*)fc0b;
  float acc = 0.f;
  #pragma unroll
  for (int u=0; u<6; ++u){
    const int j = t + u*256;
    if (j < 1500){
      const float4 a0=p0[j], a1=p1[j], a2=p2[j], a3=p3[j], bv=bb[j];
      const float4 s = make_float4(a0.x+a1.x+a2.x+a3.x+bv.x, a0.y+a1.y+a2.y+a3.y+bv.y,
                                   a0.z+a1.z+a2.z+a3.z+bv.z, a0.w+a1.w+a2.w+a3.w+bv.w);
      acc += d4(wr[j], s);
    }
  }
  acc = wredsum(acc);
  if (lane == 0) sm[wv] = acc;
  __syncthreads();
  if (t == 0) ws[WS_N1+row] = sm[0]+sm[1]+sm[2]+sm[3] + fc1b[row];
  __syncthreads();
}

struct KP {
  const float *x,*stt,*xg,*c1w,*c1b,*c2w,*c2b,*c3w,*c3b,*fc0w,*fc0b,*fc1w,*fc1b,
    *fc2w,*fc2b,*fc3w,*fc3b,*s1alw,*s1alb,*s1arw,*s1blw,*s1blb,*s1brw,
    *g2w,*g2as,*g2ad,*g2b,*s3alw,*s3alb,*s3arw,*s3blw,*s3blb,*s3brw,
    *g4w,*g4as,*g4ad,*g4b,*gcnw,*gcnb,*fcgw,*fcgb,*fc4w,*fc4b,*muw,*mub,*lsig,*crw,*crb;
  float *ws; float *out;
};

// ============================================================================
// Persistent kernel: 512 blocks x 256 threads, 11 stages / 10 manual barriers
// ============================================================================
__global__ __launch_bounds__(256, 2) void k_all(KP p)
{
  __shared__ __align__(16) float sm[9728];
  const int b = blockIdx.x, t = threadIdx.x;
  const int lane = t & 63, wv = t >> 6;
  float* ws = p.ws;
  unsigned* bar = (unsigned*)(ws + WS_BAR);

  // ---- S1: conv1(497) + sage1a(4) + state MLP(1)  [single-shot, NT=502]
  if (b < 497){
    conv1_task(b, t, p.x, p.c1w, p.c1b, ws);
  } else if (b < 501){
    const int i = (b-497)*256 + t;
    if (i < 1000){
      float xv[19];
      #pragma unroll
      for (int n=0;n<19;++n) xv[n] = p.xg[n];
      float ag[19];
      #pragma unroll
      for (int n=0;n<19;++n) ag[n]=0.f;
      #pragma unroll
      for (int e=0;e<36;++e) ag[EDST[e]] += xv[ESRC[e]];
      const float lwv=p.s1alw[i], lbv=p.s1alb[i], rwv=p.s1arw[i];
      float hc[19];
      #pragma unroll
      for (int n=0;n<19;++n){
        hc[n] = fmaxf(lwv*ag[n] + lbv + rwv*xv[n], 0.f);
        ws[WS_HA+n*1000+i] = hc[n];
      }
      #pragma unroll
      for (int n=0;n<19;++n){
        float a=0.f;
        #pragma unroll
        for (int e=0;e<36;++e) if (EDST[e]==n) a += hc[ESRC[e]];
        ws[WS_AGA+n*1000+i] = a;
      }
    }
  } else if (b == 501){
    if (t < 100){
      float acc = p.fc2b[t];
      #pragma unroll
      for (int k=0;k<20;++k) acc += p.fc2w[t*20+k]*p.stt[k];
      sm[t] = acc;
    }
    __syncthreads();
    if (t < 100){
      float acc = p.fc3b[t];
      for (int k=0;k<100;++k) acc += p.fc3w[t*100+k]*sm[k];
      ws[WS_N2+t] = acc;
    }
  }
  gridbar(bar, 0);

  // ---- S2: conv2(128) + sage1b(500)  NT=628
  for (int task = b; task < 628; task += NBLK){
    __syncthreads();
    if (task < 128) conv2_task(task, t, sm, p.c2w, p.c2b, ws);
    else sage_split<0>(task-128, t, sm, ws+WS_HA, nullptr, nullptr, ws+WS_AGA,
                       p.s1blw, p.s1brw, ws+WS_PB);
  }
  gridbar(bar, 1);

  // ---- S3: conv3(32) + gat2mm(500)  NT=532
  for (int task = b; task < 532; task += NBLK){
    __syncthreads();
    if (task < 32) conv3_task(task, t, sm, p.c3w, p.c3b, ws);
    else gatmat_split<2>(task-32, t, sm, nullptr, ws+WS_PB, p.s1blb, p.g2w, ws+WS_PH);
  }
  gridbar(bar, 2);

  // ---- S4: fc0(6000)  [LDS-free, no per-iter sync]
  for (int task = b; task < 6000; task += NBLK)
    fc0_task(task, t, p.fc0w, ws);
  gridbar(bar, 3);

  // ---- S5: fc1(100) + gat2 finisher with inline alpha(4)  [single-shot]
  if (b < 100) fc1_task(b, t, sm, p.fc1w, p.fc1b, p.fc0b, ws);
  else if (b < 104) gat_fin_task(b-100, t, sm, ws+WS_PH, p.g2as, p.g2ad, p.g2b, ws+WS_HA);
  gridbar(bar, 4);

  // ---- S6: sage3a(500)  [single-shot]
  if (b < 500)
    sage_split<1>(b, t, sm, ws+WS_HA, nullptr, nullptr, nullptr,
                  p.s3alw, p.s3arw, ws+WS_PB);
  gridbar(bar, 5);

  // ---- S7: sage3b(500)
  if (b < 500)
    sage_split<2>(b, t, sm, nullptr, ws+WS_PB, p.s3alb, nullptr,
                  p.s3blw, p.s3brw, ws+WS_PC);
  gridbar(bar, 6);

  // ---- S8: gat4mm(500)
  if (b < 500)
    gatmat_split<2>(b, t, sm, nullptr, ws+WS_PC, p.s3blb, p.g4w, ws+WS_PH);
  gridbar(bar, 7);

  // ---- S9: gat4 finisher with inline alpha(4)
  if (b < 4) gat_fin_task(b, t, sm, ws+WS_PH, p.g4as, p.g4ad, p.g4b, ws+WS_HB);
  gridbar(bar, 8);

  // ---- S10: gcn(500)
  if (b < 500)
    gatmat_split<3>(b, t, sm, ws+WS_HB, nullptr, nullptr, p.gcnw, ws+WS_PB);
  gridbar(bar, 9);

  // ---- S11: gcnfin + fcg + head (single block)
  if (b == 0){
    float cc[19];
    #pragma unroll
    for (int m=0;m<19;++m) cc[m] = 2.f*DINV[m]*DINV[m];
    #pragma unroll
    for (int e=0;e<36;++e) cc[ESRC[e]] += DINV[ESRC[e]]*DINV[EDST[e]];
    for (int i = t; i < 1000; i += 256){
      float s = p.gcnb[i];
      #pragma unroll
      for (int m=0;m<19;++m){
        const float hh = ws[WS_PB + m*1000 + i] + ws[WS_PB + (19+m)*1000 + i]
                       + ws[WS_PB + (38+m)*1000 + i] + ws[WS_PB + (57+m)*1000 + i];
        s += (cc[m]*(1.f/19.f))*hh;
      }
      sm[i] = s;
    }
    __syncthreads();
    for (int r = wv; r < 100; r += 4){
      const float4* wr4 = (const float4*)(p.fcgw + r*1000);
      const float4* gv4 = (const float4*)sm;
      float acc = 0.f;
      for (int j = lane; j < 250; j += 64) acc += d4(wr4[j], gv4[j]);
      acc = wredsum(acc);
      if (lane == 0) sm[1024+r] = acc + p.fcgb[r];
    }
    __syncthreads();
    for (int c = t; c < 300; c += 256){
      float v = (c < 100) ? ws[WS_N1+c] : (c < 200) ? ws[WS_N2+c-100] : sm[1024+c-200];
      sm[1200+c] = v;
    }
    __syncthreads();
    if (wv < 3){
      const int base = 1200 + wv*100;
      const float v  = sm[base + lane];
      const float v2 = (lane < 36) ? sm[base + 64 + lane] : v;
      float mn = fminf(v, v2), mx = fmaxf(v, v2);
      #pragma unroll
      for (int o=32;o;o>>=1){ mn = fminf(mn, __shfl_xor(mn,o)); mx = fmaxf(mx, __shfl_xor(mx,o)); }
      if (lane == 0){ sm[1500+wv*2]=mn; sm[1501+wv*2]=mx; }
    }
    __syncthreads();
    for (int c = t; c < 300; c += 256){
      const int g = c/100;
      sm[1200+c] = (sm[1200+c]-sm[1500+g*2])/(sm[1501+g*2]-sm[1500+g*2]);
    }
    __syncthreads();
    for (int r = wv; r < 200; r += 4){
      const float* wp = p.fc4w + r*300;
      float acc = 0.f;
      for (int k = lane; k < 300; k += 64) acc += wp[k]*sm[1200+k];
      acc = wredsum(acc);
      if (lane == 0) sm[1600+r] = acc + p.fc4b[r];
    }
    __syncthreads();
    if (t >= 12 && t < 24) p.out[t] = expf(p.lsig[t-12]);   // sigma
    for (int r = wv; r < 16; r += 4){
      if (r < 12){
        const float* wp = p.muw + r*200;
        float a = 0.f;
        for (int k = lane; k < 200; k += 64) a += wp[k]*sm[1600+k];
        a = wredsum(a);
        if (lane == 0) p.out[r] = tanhf(a + p.mub[r]);
      } else if (r == 12){
        float a = 0.f;
        for (int k = lane; k < 200; k += 64) a += p.crw[k]*sm[1600+k];
        a = wredsum(a);
        if (lane == 0) p.out[24] = a + p.crb[0];
      }
    }
  }
}

extern "C" void kernel_launch(void* const* d_in, const int* in_sizes, int n_in,
                              void* d_out, int out_size, void* d_ws, size_t ws_size,
                              hipStream_t stream)
{
  (void)in_sizes; (void)n_in; (void)out_size; (void)ws_size;
  KP p;
  p.x     = (const float*)d_in[0];
  p.stt   = (const float*)d_in[1];
  p.xg    = (const float*)d_in[2];
  p.c1w   = (const float*)d_in[3];
  p.c1b   = (const float*)d_in[4];
  p.c2w   = (const float*)d_in[5];
  p.c2b   = (const float*)d_in[6];
  p.c3w   = (const float*)d_in[7];
  p.c3b   = (const float*)d_in[8];
  p.fc0w  = (const float*)d_in[9];
  p.fc0b  = (const float*)d_in[10];
  p.fc1w  = (const float*)d_in[11];
  p.fc1b  = (const float*)d_in[12];
  p.fc2w  = (const float*)d_in[13];
  p.fc2b  = (const float*)d_in[14];
  p.fc3w  = (const float*)d_in[15];
  p.fc3b  = (const float*)d_in[16];
  p.s1alw = (const float*)d_in[17];
  p.s1alb = (const float*)d_in[18];
  p.s1arw = (const float*)d_in[19];
  p.s1blw = (const float*)d_in[20];
  p.s1blb = (const float*)d_in[21];
  p.s1brw = (const float*)d_in[22];
  p.g2w   = (const float*)d_in[23];
  p.g2as  = (const float*)d_in[24];
  p.g2ad  = (const float*)d_in[25];
  p.g2b   = (const float*)d_in[26];
  p.s3alw = (const float*)d_in[27];
  p.s3alb = (const float*)d_in[28];
  p.s3arw = (const float*)d_in[29];
  p.s3blw = (const float*)d_in[30];
  p.s3blb = (const float*)d_in[31];
  p.s3brw = (const float*)d_in[32];
  p.g4w   = (const float*)d_in[33];
  p.g4as  = (const float*)d_in[34];
  p.g4ad  = (const float*)d_in[35];
  p.g4b   = (const float*)d_in[36];
  p.gcnw  = (const float*)d_in[37];
  p.gcnb  = (const float*)d_in[38];
  p.fcgw  = (const float*)d_in[39];
  p.fcgb  = (const float*)d_in[40];
  p.fc4w  = (const float*)d_in[41];
  p.fc4b  = (const float*)d_in[42];
  p.muw   = (const float*)d_in[43];
  p.mub   = (const float*)d_in[44];
  p.lsig  = (const float*)d_in[45];
  p.crw   = (const float*)d_in[46];
  p.crb   = (const float*)d_in[47];
  p.ws    = (float*)d_ws;
  p.out   = (float*)d_out;

  // zero the barrier counters (graph-capturable memset node)
  hipMemsetAsync((char*)d_ws + (size_t)WS_BAR*4, 0, 64, stream);
  k_all<<<dim3(NBLK), dim3(256), 0, stream>>>(p);
}

// Round 8
// 413.936 us; speedup vs baseline: 5.6737x; 5.6737x over previous
//
#include <hip/hip_runtime.h>
#include <math.h>

#define DEV __device__ __forceinline__

// ---------------- graph constants ----------------
constexpr int ESRC[36] = {0,1,2,3,4,5,6,7,8,9,10,11,12,13,14,15,16,17,18,1,2,3,4,5,6,7,8,9,10,11,12,13,14,15,16,17};
constexpr int EDST[36] = {1,2,3,4,5,6,7,8,9,10,11,12,13,14,15,16,17,18,17,0,1,2,3,4,5,6,7,8,9,10,11,12,13,14,15,16};
constexpr int SSRC[55] = {0,1,2,3,4,5,6,7,8,9,10,11,12,13,14,15,16,17,18,1,2,3,4,5,6,7,8,9,10,11,12,13,14,15,16,17,
                          0,1,2,3,4,5,6,7,8,9,10,11,12,13,14,15,16,17,18};
constexpr int SDST[55] = {1,2,3,4,5,6,7,8,9,10,11,12,13,14,15,16,17,18,17,0,1,2,3,4,5,6,7,8,9,10,11,12,13,14,15,16,
                          0,1,2,3,4,5,6,7,8,9,10,11,12,13,14,15,16,17,18};
constexpr float DINV[19] = {0.5773502691896258f,0.5f,0.5f,0.5f,0.5f,0.5f,0.5f,0.5f,0.5f,0.5f,
                            0.5f,0.5f,0.5f,0.5f,0.5f,0.5f,0.5f,0.5f,0.5773502691896258f};

// ---------------- workspace layout (float offsets) ----------------
constexpr int WS_C1  = 0;        // 32*63*63 = 127008 (dead after K2)
constexpr int WS_C2  = 127008;   // 32*30*30 = 28800
constexpr int WS_V   = 155808;   // 6272
constexpr int WS_FC0 = 162080;   // 6000 (fc0 partial q0; NO bias)
constexpr int WS_N1  = 168080;   // 100
constexpr int WS_N2  = 168180;   // 100
constexpr int WS_HA  = 168280;   // 19*1000 (h2 = gat2 output)
constexpr int WS_FC0B= 206280;   // 6000 (fc0 partial q1)
constexpr int WS_PB  = 264384;   // 76000 partials ping (sage1b -> gat2mm; sage3a; gcn -> head)
constexpr int WS_PC  = 340384;   // 76000 partials pong (sage3b -> gat4mm)
constexpr int WS_FC0C= 416384;   // 6000 (fc0 partial q2)
constexpr int WS_FC0D= 422384;   // 6000 (fc0 partial q3)
constexpr int WS_PH2 = 428384;   // 76000 gat mm partials (gat2mm / gat4mm) end 504384

DEV float wredsum(float v){
  #pragma unroll
  for (int o = 32; o; o >>= 1) v += __shfl_xor(v, o);
  return v;
}
DEV float d4(float4 a, float4 b){ return a.x*b.x + a.y*b.y + a.z*b.z + a.w*b.w; }

// ============================================================================
// SAGE split matmul task (verified body from R5)
// MODE 1: stage h from global, compute agg. MODE 2: h = relu(4 partials+bias).
// ============================================================================
template<int MODE>
DEV void sage_split(int blk, int tid, float* sm,
                    const float* hin, const float* pin,
                    const float* pbias,
                    const float* lw, const float* rw, float* pout)
{
  const int cg_ = blk >> 2, kq = blk & 3;
  const int kb = kq*256;
  const int cntf = (kq < 3) ? 256 : 232;
  const int cnt4 = cntf >> 2;
  float* hS = sm;            // [19][256]
  float* aS = sm + 19*256;   // [19][256]
  if (MODE == 2){
    for (int c = tid; c < 19*256; c += 256){
      const int n = c >> 8, j = c & 255;
      if (j < cntf){
        const int i = kb + j;
        const float v = pin[n*1000+i] + pin[(19+n)*1000+i] + pin[(38+n)*1000+i]
                      + pin[(57+n)*1000+i] + pbias[i];
        hS[c] = fmaxf(v, 0.f);
      }
    }
  } else {
    for (int c = tid; c < 19*64; c += 256){
      const int n = c >> 6, j = c & 63;
      if (j < cnt4)
        ((float4*)hS)[n*64 + j] = *(const float4*)(hin + n*1000 + kb + 4*j);
    }
  }
  __syncthreads();
  if (tid < cntf){
    float hv[19];
    #pragma unroll
    for (int n=0;n<19;++n) hv[n] = hS[n*256 + tid];
    float ag[19];
    #pragma unroll
    for (int n=0;n<19;++n) ag[n] = 0.f;
    #pragma unroll
    for (int e=0;e<36;++e) ag[EDST[e]] += hv[ESRC[e]];
    #pragma unroll
    for (int n=0;n<19;++n) aS[n*256 + tid] = ag[n];
  }
  __syncthreads();
  const int lane = tid & 63, wv = tid >> 6;
  const int i0 = cg_*8 + 2*wv, i1 = i0 + 1;
  float acc0[19], acc1[19];
  #pragma unroll
  for (int n=0;n<19;++n){ acc0[n]=0.f; acc1[n]=0.f; }
  if (lane < cnt4){
    const float4 wl0 = *((const float4*)(lw + i0*1000) + kq*64 + lane);
    const float4 wl1 = *((const float4*)(lw + i1*1000) + kq*64 + lane);
    const float4 wr0 = *((const float4*)(rw + i0*1000) + kq*64 + lane);
    const float4 wr1 = *((const float4*)(rw + i1*1000) + kq*64 + lane);
    const float4* h4 = (const float4*)hS;
    const float4* a4 = (const float4*)aS;
    #pragma unroll
    for (int n=0;n<19;++n){
      const float4 hv = h4[n*64+lane], av = a4[n*64+lane];
      acc0[n] = d4(wl0,av) + d4(wr0,hv);
      acc1[n] = d4(wl1,av) + d4(wr1,hv);
    }
  }
  #pragma unroll
  for (int n=0;n<19;++n){ acc0[n]=wredsum(acc0[n]); acc1[n]=wredsum(acc1[n]); }
  if (lane == 0){
    #pragma unroll
    for (int n=0;n<19;++n){
      pout[(kq*19+n)*1000 + i0] = acc0[n];
      pout[(kq*19+n)*1000 + i1] = acc1[n];
    }
  }
}

// ============================================================================
// sage1b with INLINE sage1a: stage h1 chunk directly from xg + sage1a params
// ============================================================================
DEV void sage1b_fused(int blk, int tid, float* sm, const float* xg,
                      const float* alw, const float* alb, const float* arw,
                      const float* lw, const float* rw, float* pout)
{
  const int cg_ = blk >> 2, kq = blk & 3;
  const int kb = kq*256;
  const int cntf = (kq < 3) ? 256 : 232;
  const int cnt4 = cntf >> 2;
  float* hS = sm;            // [19][256]
  float* aS = sm + 19*256;   // [19][256]
  float xv[19];
  #pragma unroll
  for (int n=0;n<19;++n) xv[n] = xg[n];
  float ag0[19];
  #pragma unroll
  for (int n=0;n<19;++n) ag0[n] = 0.f;
  #pragma unroll
  for (int e=0;e<36;++e) ag0[EDST[e]] += xv[ESRC[e]];
  if (tid < cntf){
    const int i = kb + tid;
    const float a = alw[i], bb = alb[i], r = arw[i];
    float hv[19];
    #pragma unroll
    for (int n=0;n<19;++n){ hv[n] = fmaxf(a*ag0[n] + bb + r*xv[n], 0.f); hS[n*256+tid] = hv[n]; }
    float ag[19];
    #pragma unroll
    for (int n=0;n<19;++n) ag[n] = 0.f;
    #pragma unroll
    for (int e=0;e<36;++e) ag[EDST[e]] += hv[ESRC[e]];
    #pragma unroll
    for (int n=0;n<19;++n) aS[n*256+tid] = ag[n];
  }
  __syncthreads();
  const int lane = tid & 63, wv = tid >> 6;
  const int i0 = cg_*8 + 2*wv, i1 = i0 + 1;
  float acc0[19], acc1[19];
  #pragma unroll
  for (int n=0;n<19;++n){ acc0[n]=0.f; acc1[n]=0.f; }
  if (lane < cnt4){
    const float4 wl0 = *((const float4*)(lw + i0*1000) + kq*64 + lane);
    const float4 wl1 = *((const float4*)(lw + i1*1000) + kq*64 + lane);
    const float4 wr0 = *((const float4*)(rw + i0*1000) + kq*64 + lane);
    const float4 wr1 = *((const float4*)(rw + i1*1000) + kq*64 + lane);
    const float4* h4 = (const float4*)hS;
    const float4* a4 = (const float4*)aS;
    #pragma unroll
    for (int n=0;n<19;++n){
      const float4 hv = h4[n*64+lane], av = a4[n*64+lane];
      acc0[n] = d4(wl0,av) + d4(wr0,hv);
      acc1[n] = d4(wl1,av) + d4(wr1,hv);
    }
  }
  #pragma unroll
  for (int n=0;n<19;++n){ acc0[n]=wredsum(acc0[n]); acc1[n]=wredsum(acc1[n]); }
  if (lane == 0){
    #pragma unroll
    for (int n=0;n<19;++n){
      pout[(kq*19+n)*1000 + i0] = acc0[n];
      pout[(kq*19+n)*1000 + i1] = acc1[n];
    }
  }
}

// ============================================================================
// GAT/GCN split matmul task (verified body from R5)
// MODE 2: h = relu(4 sage partials + bias); MODE 3: copy full h.
// ============================================================================
template<int MODE>
DEV void gatmat_split(int blk, int tid, float* sm,
                      const float* hin, const float* pin, const float* pbias,
                      const float* W, float* pout)
{
  const int cg_ = blk >> 2, kq = blk & 3;
  const int kb = kq*256;
  const int cntf = (kq < 3) ? 256 : 232;
  const int cnt4 = cntf >> 2;
  float* hS = sm;
  if (MODE == 2){
    for (int c = tid; c < 19*256; c += 256){
      const int n = c >> 8, j = c & 255;
      if (j < cntf){
        const int i = kb + j;
        const float v = pin[n*1000+i] + pin[(19+n)*1000+i] + pin[(38+n)*1000+i]
                      + pin[(57+n)*1000+i] + pbias[i];
        hS[c] = fmaxf(v, 0.f);
      }
    }
  } else {
    for (int c = tid; c < 19*64; c += 256){
      const int n = c >> 6, j = c & 63;
      if (j < cnt4)
        ((float4*)hS)[n*64 + j] = *(const float4*)(hin + n*1000 + kb + 4*j);
    }
  }
  __syncthreads();
  const int lane = tid & 63, wv = tid >> 6;
  const int i0 = cg_*8 + 2*wv, i1 = i0 + 1;
  float acc0[19], acc1[19];
  #pragma unroll
  for (int n=0;n<19;++n){ acc0[n]=0.f; acc1[n]=0.f; }
  if (lane < cnt4){
    const float4 w0 = *((const float4*)(W + i0*1000) + kq*64 + lane);
    const float4 w1 = *((const float4*)(W + i1*1000) + kq*64 + lane);
    const float4* h4 = (const float4*)hS;
    #pragma unroll
    for (int n=0;n<19;++n){
      const float4 hv = h4[n*64+lane];
      acc0[n] = d4(w0,hv);
      acc1[n] = d4(w1,hv);
    }
  }
  #pragma unroll
  for (int n=0;n<19;++n){ acc0[n]=wredsum(acc0[n]); acc1[n]=wredsum(acc1[n]); }
  if (lane == 0){
    #pragma unroll
    for (int n=0;n<19;++n){
      pout[(kq*19+n)*1000 + i0] = acc0[n];
      pout[(kq*19+n)*1000 + i1] = acc1[n];
    }
  }
}

// ---- alpha into sm[320..374] (redundant per calling block, deterministic) ----
DEV void alpha_sm(int t, float* sm, const float* ph, const float* as_,
                  const float* ad_)
{
  const int lane = t & 63, wv = t >> 6;
  float es[19], ed[19];
  #pragma unroll
  for (int n=0;n<19;++n){ es[n]=0.f; ed[n]=0.f; }
  for (int k = t; k < 1000; k += 256){
    const float asv = as_[k], adv = ad_[k];
    #pragma unroll
    for (int n=0;n<19;++n){
      const float hh = ph[n*1000+k] + ph[(19+n)*1000+k] + ph[(38+n)*1000+k] + ph[(57+n)*1000+k];
      es[n] += hh*asv; ed[n] += hh*adv;
    }
  }
  #pragma unroll
  for (int n=0;n<19;++n){ es[n]=wredsum(es[n]); ed[n]=wredsum(ed[n]); }
  if (lane == 0){
    #pragma unroll
    for (int n=0;n<19;++n){ sm[wv*38+n]=es[n]; sm[wv*38+19+n]=ed[n]; }
  }
  __syncthreads();
  if (t < 38) sm[152+t] = sm[t] + sm[38+t] + sm[76+t] + sm[114+t]; // es:152 ed:171
  __syncthreads();
  if (t < 55){
    float e = sm[152+SSRC[t]] + sm[171+SDST[t]];
    sm[200+t] = e > 0.f ? e : 0.2f*e;
  }
  __syncthreads();
  if (t < 19){
    float m = -1e30f;
    #pragma unroll
    for (int e=0;e<55;++e) if (SDST[e]==t) m = fmaxf(m, sm[200+e]);
    float den = 0.f;
    #pragma unroll
    for (int e=0;e<55;++e) if (SDST[e]==t) den += expf(sm[200+e]-m);
    sm[260+t]=m; sm[280+t]=den;
  }
  __syncthreads();
  if (t < 55) sm[320+t] = expf(sm[200+t]-sm[260+SDST[t]]) / sm[280+SDST[t]];
  __syncthreads();
}

// ---- gat finisher task: inline alpha + per-column aggregation chunk ----
DEV void gat_fin_task(int blk, int t, float* sm, const float* ph,
                      const float* as_, const float* ad_,
                      const float* bias, float* hout)
{
  alpha_sm(t, sm, ph, as_, ad_);
  const int i = blk*256 + t;
  if (i < 1000){
    float hv[19];
    #pragma unroll
    for (int n=0;n<19;++n)
      hv[n] = ph[n*1000+i] + ph[(19+n)*1000+i] + ph[(38+n)*1000+i] + ph[(57+n)*1000+i];
    float acc[19];
    #pragma unroll
    for (int n=0;n<19;++n) acc[n]=0.f;
    #pragma unroll
    for (int e=0;e<55;++e) acc[SDST[e]] += sm[320+e]*hv[SSRC[e]];
    const float bi = bias[i];
    #pragma unroll
    for (int n=0;n<19;++n) hout[n*1000+i] = fmaxf(acc[n]+bi, 0.f);
  }
}

// ---- gcn matmul with INLINE gat4 finisher: rebuild hb chunk from partials ----
DEV void gcn_fused_task(int blk, int t, float* sm, const float* ph,
                        const float* as_, const float* ad_, const float* bias,
                        const float* W, float* pout)
{
  alpha_sm(t, sm, ph, as_, ad_);          // sm[320..374]
  const int cg_ = blk >> 2, kq = blk & 3;
  const int kb = kq*256;
  const int cntf = (kq < 3) ? 256 : 232;
  const int cnt4 = cntf >> 2;
  float* hS = sm + 384;                    // [19][256]
  if (t < cntf){
    const int i = kb + t;
    float hv[19];
    #pragma unroll
    for (int n=0;n<19;++n)
      hv[n] = ph[n*1000+i] + ph[(19+n)*1000+i] + ph[(38+n)*1000+i] + ph[(57+n)*1000+i];
    float acc[19];
    #pragma unroll
    for (int n=0;n<19;++n) acc[n]=0.f;
    #pragma unroll
    for (int e=0;e<55;++e) acc[SDST[e]] += sm[320+e]*hv[SSRC[e]];
    const float bi = bias[i];
    #pragma unroll
    for (int n=0;n<19;++n) hS[n*256+t] = fmaxf(acc[n]+bi, 0.f);
  }
  __syncthreads();
  const int lane = t & 63, wv = t >> 6;
  const int i0 = cg_*8 + 2*wv, i1 = i0 + 1;
  float acc0[19], acc1[19];
  #pragma unroll
  for (int n=0;n<19;++n){ acc0[n]=0.f; acc1[n]=0.f; }
  if (lane < cnt4){
    const float4 w0 = *((const float4*)(W + i0*1000) + kq*64 + lane);
    const float4 w1 = *((const float4*)(W + i1*1000) + kq*64 + lane);
    const float4* h4 = (const float4*)hS;
    #pragma unroll
    for (int n=0;n<19;++n){
      const float4 hv = h4[n*64+lane];
      acc0[n] = d4(w0,hv);
      acc1[n] = d4(w1,hv);
    }
  }
  #pragma unroll
  for (int n=0;n<19;++n){ acc0[n]=wredsum(acc0[n]); acc1[n]=wredsum(acc1[n]); }
  if (lane == 0){
    #pragma unroll
    for (int n=0;n<19;++n){
      pout[(kq*19+n)*1000 + i0] = acc0[n];
      pout[(kq*19+n)*1000 + i1] = acc1[n];
    }
  }
}

// ---- conv tasks (verified bodies from R5) ----
DEV void conv1_task(int task, int t, const float* x, const float* c1w,
                    const float* c1b, float* ws)
{
  const int idx = task*256 + t;
  if (idx < 127008){
    const int oc = idx/3969, r = idx - oc*3969, oy = r/63, ox = r - oy*63;
    const float* wp = c1w + oc*25;
    float acc = c1b[oc];
    #pragma unroll
    for (int ky=0;ky<5;++ky){
      const int iy = oy*2 - 1 + ky;
      if ((unsigned)iy < 128u){
        #pragma unroll
        for (int kx=0;kx<5;++kx){
          const int ix = ox*2 - 1 + kx;
          if ((unsigned)ix < 128u) acc += x[iy*128+ix]*wp[ky*5+kx];
        }
      }
    }
    ws[WS_C1+idx] = fmaxf(acc, 0.f);
  }
}

DEV void conv2_task(int task, int t, float* sm, const float* c2w,
                    const float* c2b, float* ws)
{
  const int oc = task >> 2, q = task & 3;
  const int r0 = q*16;
  const int nout = (q < 3) ? 240 : 180;
  float* buf0 = sm; float* buf1 = sm + 4788;
  float rv[19];
  #pragma unroll
  for (int u=0; u<19; ++u){
    const int c = t + u*256; float v = 0.f;
    if (c < 4788){
      const int p = c/1197, r = c - p*1197, lr = r/63, xx = r - lr*63;
      const int iy = r0 + lr;
      if (iy < 63) v = ws[WS_C1 + p*3969 + iy*63 + xx];
    }
    rv[u] = v;
  }
  #pragma unroll
  for (int u=0; u<19; ++u){ const int c = t+u*256; if (c<4788) buf0[c]=rv[u]; }
  __syncthreads();
  const int oy_l = t/30, ox = t - oy_l*30;
  float acc = (t < nout) ? c2b[oc] : 0.f;
  for (int g=0; g<8; ++g){
    float* cur = (g&1) ? buf1 : buf0;
    if (g < 7){
      #pragma unroll
      for (int u=0; u<19; ++u){
        const int c = t + u*256; float v = 0.f;
        if (c < 4788){
          const int p = c/1197, r = c - p*1197, lr = r/63, xx = r - lr*63;
          const int iy = r0 + lr;
          if (iy < 63) v = ws[WS_C1 + (4*(g+1)+p)*3969 + iy*63 + xx];
        }
        rv[u] = v;
      }
    }
    if (t < nout){
      #pragma unroll
      for (int p=0;p<4;++p){
        const float* wp = c2w + (oc*32 + 4*g + p)*25;
        const float* ip = cur + p*1197 + (2*oy_l)*63 + 2*ox;
        #pragma unroll
        for (int ky=0;ky<5;++ky)
          #pragma unroll
          for (int kx=0;kx<5;++kx)
            acc += ip[ky*63+kx]*wp[ky*5+kx];
      }
    }
    if (g < 7){
      __syncthreads();
      float* nxt = (g&1) ? buf0 : buf1;
      #pragma unroll
      for (int u=0; u<19; ++u){ const int c = t+u*256; if (c<4788) nxt[c]=rv[u]; }
      __syncthreads();
    }
  }
  if (t < nout){
    const int oy = q*8 + oy_l;
    ws[WS_C2 + oc*900 + oy*30 + ox] = fmaxf(acc, 0.f);
  }
}

DEV void conv3_task(int oc, int t, float* sm, const float* c3w,
                    const float* c3b, float* ws)
{
  float* buf0 = sm; float* buf1 = sm + 3600;
  float rv[15];
  #pragma unroll
  for (int u=0; u<15; ++u){
    const int c = t + u*256;
    rv[u] = (c < 3600) ? ws[WS_C2 + c] : 0.f;
  }
  #pragma unroll
  for (int u=0; u<15; ++u){ const int c = t+u*256; if (c<3600) buf0[c]=rv[u]; }
  __syncthreads();
  const int oy = t/14, ox = t - oy*14;
  float acc = (t < 196) ? c3b[oc] : 0.f;
  for (int g=0; g<8; ++g){
    float* cur = (g&1) ? buf1 : buf0;
    if (g < 7){
      #pragma unroll
      for (int u=0; u<15; ++u){
        const int c = t + u*256;
        rv[u] = (c < 3600) ? ws[WS_C2 + (g+1)*3600 + c] : 0.f;
      }
    }
    if (t < 196){
      #pragma unroll
      for (int p=0;p<4;++p){
        const float* wp = c3w + (oc*32 + 4*g + p)*25;
        const float* ip = cur + p*900;
        #pragma unroll
        for (int ky=0;ky<5;++ky){
          const int iy = oy*2 - 1 + ky;
          if ((unsigned)iy < 30u){
            #pragma unroll
            for (int kx=0;kx<5;++kx){
              const int ix = ox*2 - 1 + kx;
              if ((unsigned)ix < 30u) acc += ip[iy*30+ix]*wp[ky*5+kx];
            }
          }
        }
      }
    }
    if (g < 7){
      __syncthreads();
      float* nxt = (g&1) ? buf0 : buf1;
      #pragma unroll
      for (int u=0; u<15; ++u){ const int c = t+u*256; if (c<3600) nxt[c]=rv[u]; }
      __syncthreads();
    }
  }
  if (t < 196) ws[WS_V + oc*196 + t] = acc;  // no relu on conv3
}

// ---- fc0 task: quarter-row of 4 rows, LDS-free, reg-batched ----
DEV void fc0_task(int task, int t, const float* fc0w, float* ws)
{
  const int lane = t & 63, wv = t >> 6;
  const int rq = task >> 2, q = task & 3;
  const int row = rq*4 + wv;
  const float4* vr = (const float4*)(ws + WS_V) + q*392;
  const float4* wr = (const float4*)(fc0w) + (size_t)row*1568 + q*392;
  float4 wreg[6];
  #pragma unroll
  for (int u=0; u<6; ++u) wreg[u] = wr[u*64 + lane];
  float4 wtail;
  if (lane < 8) wtail = wr[384 + lane];
  float acc = 0.f;
  #pragma unroll
  for (int u=0; u<6; ++u) acc += d4(wreg[u], vr[u*64 + lane]);
  if (lane < 8) acc += d4(wtail, vr[384 + lane]);
  acc = wredsum(acc);
  if (lane == 0){
    float* pout = ws + (q==0 ? WS_FC0 : q==1 ? WS_FC0B : q==2 ? WS_FC0C : WS_FC0D);
    pout[row] = acc;   // bias added in fc1 consumer
  }
}

// =================== K1: conv1(497) + sage1b-fused(500) + state MLP(1) ===================
__global__ __launch_bounds__(256) void k_ac_1(
    const float* __restrict__ x, const float* __restrict__ c1w, const float* __restrict__ c1b,
    const float* __restrict__ xg,
    const float* __restrict__ s1alw, const float* __restrict__ s1alb, const float* __restrict__ s1arw,
    const float* __restrict__ s1blw, const float* __restrict__ s1brw,
    const float* __restrict__ stt, const float* __restrict__ fc2w, const float* __restrict__ fc2b,
    const float* __restrict__ fc3w, const float* __restrict__ fc3b,
    float* __restrict__ ws)
{
  __shared__ __align__(16) float sm[9728];
  const int b = blockIdx.x, t = threadIdx.x;
  if (b < 497){
    conv1_task(b, t, x, c1w, c1b, ws);
  } else if (b < 997){
    sage1b_fused(b-497, t, sm, xg, s1alw, s1alb, s1arw, s1blw, s1brw, ws+WS_PB);
  } else {
    if (t < 100){
      float acc = fc2b[t];
      #pragma unroll
      for (int k=0;k<20;++k) acc += fc2w[t*20+k]*stt[k];
      sm[t] = acc;
    }
    __syncthreads();
    if (t < 100){
      float acc = fc3b[t];
      for (int k=0;k<100;++k) acc += fc3w[t*100+k]*sm[k];
      ws[WS_N2+t] = acc;
    }
  }
}

// =================== K2: conv2(128) + gat2mm(500) ===================
__global__ __launch_bounds__(256) void k_ac_2(
    const float* __restrict__ c2w, const float* __restrict__ c2b,
    const float* __restrict__ s1blb, const float* __restrict__ g2w,
    float* __restrict__ ws)
{
  __shared__ __align__(16) float sm[9728];
  const int b = blockIdx.x, t = threadIdx.x;
  if (b < 128) conv2_task(b, t, sm, c2w, c2b, ws);
  else gatmat_split<2>(b-128, t, sm, nullptr, ws+WS_PB, s1blb, g2w, ws+WS_PH2);
}

// =================== K3: conv3(32) + gat2fin(4, inline alpha) ===================
__global__ __launch_bounds__(256) void k_ac_3(
    const float* __restrict__ c3w, const float* __restrict__ c3b,
    const float* __restrict__ g2as, const float* __restrict__ g2ad, const float* __restrict__ g2b,
    float* __restrict__ ws)
{
  __shared__ __align__(16) float sm[7200];
  const int b = blockIdx.x, t = threadIdx.x;
  if (b < 32) conv3_task(b, t, sm, c3w, c3b, ws);
  else gat_fin_task(b-32, t, sm, ws+WS_PH2, g2as, g2ad, g2b, ws+WS_HA);
}

// =================== K4: fc0(6000) + sage3a(500) ===================
__global__ __launch_bounds__(256) void k_ac_4(
    const float* __restrict__ fc0w,
    const float* __restrict__ s3alw, const float* __restrict__ s3arw,
    float* __restrict__ ws)
{
  __shared__ __align__(16) float sm[9728];
  const int b = blockIdx.x, t = threadIdx.x;
  if (b < 6000) fc0_task(b, t, fc0w, ws);
  else sage_split<1>(b-6000, t, sm, ws+WS_HA, nullptr, nullptr, s3alw, s3arw, ws+WS_PB);
}

// =================== K5: fc1(100) + sage3b(500) ===================
__global__ __launch_bounds__(256) void k_ac_5(
    const float* __restrict__ fc1w, const float* __restrict__ fc1b,
    const float* __restrict__ fc0b,
    const float* __restrict__ s3alb, const float* __restrict__ s3blw, const float* __restrict__ s3brw,
    float* __restrict__ ws)
{
  __shared__ __align__(16) float sm[9728];
  const int b = blockIdx.x, t = threadIdx.x;
  if (b < 100){
    const int row = b, lane = t & 63, wv = t >> 6;
    const float4* wr = (const float4*)(fc1w + row*6000);
    const float4* p0 = (const float4*)(ws + WS_FC0);
    const float4* p1 = (const float4*)(ws + WS_FC0B);
    const float4* p2 = (const float4*)(ws + WS_FC0C);
    const float4* p3 = (const float4*)(ws + WS_FC0D);
    const float4* bb = (const float4*)fc0b;
    float acc = 0.f;
    #pragma unroll
    for (int u=0; u<6; ++u){
      const int j = t + u*256;
      if (j < 1500){
        const float4 a0=p0[j], a1=p1[j], a2=p2[j], a3=p3[j], bv=bb[j];
        const float4 s = make_float4(a0.x+a1.x+a2.x+a3.x+bv.x, a0.y+a1.y+a2.y+a3.y+bv.y,
                                     a0.z+a1.z+a2.z+a3.z+bv.z, a0.w+a1.w+a2.w+a3.w+bv.w);
        acc += d4(wr[j], s);
      }
    }
    acc = wredsum(acc);
    if (lane == 0) sm[wv] = acc;
    __syncthreads();
    if (t == 0) ws[WS_N1+row] = sm[0]+sm[1]+sm[2]+sm[3] + fc1b[row];
  } else {
    sage_split<2>(b-100, t, sm, nullptr, ws+WS_PB, s3alb, s3blw, s3brw, ws+WS_PC);
  }
}

// =================== K6: gat4mm(500) ===================
__global__ __launch_bounds__(256) void k_ac_6(
    const float* __restrict__ s3blb, const float* __restrict__ g4w, float* __restrict__ ws)
{
  __shared__ __align__(16) float sm[4864];
  gatmat_split<2>(blockIdx.x, threadIdx.x, sm, nullptr, ws+WS_PC, s3blb, g4w, ws+WS_PH2);
}

// =================== K7: gcn(500) with inline gat4fin reconstruction ===================
__global__ __launch_bounds__(256) void k_ac_7(
    const float* __restrict__ g4as, const float* __restrict__ g4ad, const float* __restrict__ g4b,
    const float* __restrict__ gcnw, float* __restrict__ ws)
{
  __shared__ __align__(16) float sm[5248];
  gcn_fused_task(blockIdx.x, threadIdx.x, sm, ws+WS_PH2, g4as, g4ad, g4b, gcnw, ws+WS_PB);
}

// =================== K8: gcnfin + fcg + head (single block) ===================
__global__ __launch_bounds__(256) void k_ac_head(
    const float* __restrict__ gcnb, const float* __restrict__ fcgw, const float* __restrict__ fcgb,
    const float* __restrict__ fc4w, const float* __restrict__ fc4b,
    const float* __restrict__ muw, const float* __restrict__ mub,
    const float* __restrict__ lsig, const float* __restrict__ crw, const float* __restrict__ crb,
    float* __restrict__ ws, float* __restrict__ out)
{
  __shared__ __align__(16) float sm[1808];
  const int t = threadIdx.x, lane = t & 63, wv = t >> 6;
  __shared__ __align__(16) float gv[1000];
  float cc[19];
  #pragma unroll
  for (int m=0;m<19;++m) cc[m] = 2.f*DINV[m]*DINV[m];
  #pragma unroll
  for (int e=0;e<36;++e) cc[ESRC[e]] += DINV[ESRC[e]]*DINV[EDST[e]];
  for (int i = t; i < 1000; i += 256){
    float s = gcnb[i];
    #pragma unroll
    for (int m=0;m<19;++m){
      const float hh = ws[WS_PB + m*1000 + i] + ws[WS_PB + (19+m)*1000 + i]
                     + ws[WS_PB + (38+m)*1000 + i] + ws[WS_PB + (57+m)*1000 + i];
      s += (cc[m]*(1.f/19.f))*hh;
    }
    gv[i] = s;
  }
  __syncthreads();
  // fcg: 100 rows
  for (int r = wv; r < 100; r += 4){
    const float4* wr4 = (const float4*)(fcgw + r*1000);
    const float4* gv4 = (const float4*)gv;
    float acc = 0.f;
    for (int j = lane; j < 250; j += 64) acc += d4(wr4[j], gv4[j]);
    acc = wredsum(acc);
    if (lane == 0) sm[1024+r] = acc + fcgb[r];
  }
  __syncthreads();
  for (int c = t; c < 300; c += 256){
    float v = (c < 100) ? ws[WS_N1+c] : (c < 200) ? ws[WS_N2+c-100] : sm[1024+c-200];
    sm[1200+c] = v;
  }
  __syncthreads();
  if (wv < 3){
    const int base = 1200 + wv*100;
    const float v  = sm[base + lane];
    const float v2 = (lane < 36) ? sm[base + 64 + lane] : v;
    float mn = fminf(v, v2), mx = fmaxf(v, v2);
    #pragma unroll
    for (int o=32;o;o>>=1){ mn = fminf(mn, __shfl_xor(mn,o)); mx = fmaxf(mx, __shfl_xor(mx,o)); }
    if (lane == 0){ sm[1500+wv*2]=mn; sm[1501+wv*2]=mx; }
  }
  __syncthreads();
  for (int c = t; c < 300; c += 256){
    const int g = c/100;
    sm[1200+c] = (sm[1200+c]-sm[1500+g*2])/(sm[1501+g*2]-sm[1500+g*2]);
  }
  __syncthreads();
  for (int r = wv; r < 200; r += 4){
    const float* wp = fc4w + r*300;
    float acc = 0.f;
    for (int k = lane; k < 300; k += 64) acc += wp[k]*sm[1200+k];
    acc = wredsum(acc);
    if (lane == 0) sm[1600+r] = acc + fc4b[r];
  }
  __syncthreads();
  if (t >= 12 && t < 24) out[t] = expf(lsig[t-12]);   // sigma
  for (int r = wv; r < 16; r += 4){
    if (r < 12){
      const float* wp = muw + r*200;
      float a = 0.f;
      for (int k = lane; k < 200; k += 64) a += wp[k]*sm[1600+k];
      a = wredsum(a);
      if (lane == 0) out[r] = tanhf(a + mub[r]);
    } else if (r == 12){
      float a = 0.f;
      for (int k = lane; k < 200; k += 64) a += crw[k]*sm[1600+k];
      a = wredsum(a);
      if (lane == 0) out[24] = a + crb[0];
    }
  }
}

extern "C" void kernel_launch(void* const* d_in, const int* in_sizes, int n_in,
                              void* d_out, int out_size, void* d_ws, size_t ws_size,
                              hipStream_t stream)
{
  (void)in_sizes; (void)n_in; (void)out_size; (void)ws_size;
  const float* x     = (const float*)d_in[0];
  const float* stt   = (const float*)d_in[1];
  const float* xg    = (const float*)d_in[2];
  const float* c1w   = (const float*)d_in[3];
  const float* c1b   = (const float*)d_in[4];
  const float* c2w   = (const float*)d_in[5];
  const float* c2b   = (const float*)d_in[6];
  const float* c3w   = (const float*)d_in[7];
  const float* c3b   = (const float*)d_in[8];
  const float* fc0w  = (const float*)d_in[9];
  const float* fc0b  = (const float*)d_in[10];
  const float* fc1w  = (const float*)d_in[11];
  const float* fc1b  = (const float*)d_in[12];
  const float* fc2w  = (const float*)d_in[13];
  const float* fc2b  = (const float*)d_in[14];
  const float* fc3w  = (const float*)d_in[15];
  const float* fc3b  = (const float*)d_in[16];
  const float* s1alw = (const float*)d_in[17];
  const float* s1alb = (const float*)d_in[18];
  const float* s1arw = (const float*)d_in[19];
  const float* s1blw = (const float*)d_in[20];
  const float* s1blb = (const float*)d_in[21];
  const float* s1brw = (const float*)d_in[22];
  const float* g2w   = (const float*)d_in[23];
  const float* g2as  = (const float*)d_in[24];
  const float* g2ad  = (const float*)d_in[25];
  const float* g2b   = (const float*)d_in[26];
  const float* s3alw = (const float*)d_in[27];
  const float* s3alb = (const float*)d_in[28];
  const float* s3arw = (const float*)d_in[29];
  const float* s3blw = (const float*)d_in[30];
  const float* s3blb = (const float*)d_in[31];
  const float* s3brw = (const float*)d_in[32];
  const float* g4w   = (const float*)d_in[33];
  const float* g4as  = (const float*)d_in[34];
  const float* g4ad  = (const float*)d_in[35];
  const float* g4b   = (const float*)d_in[36];
  const float* gcnw  = (const float*)d_in[37];
  const float* gcnb  = (const float*)d_in[38];
  const float* fcgw  = (const float*)d_in[39];
  const float* fcgb  = (const float*)d_in[40];
  const float* fc4w  = (const float*)d_in[41];
  const float* fc4b  = (const float*)d_in[42];
  const float* muw   = (const float*)d_in[43];
  const float* mub   = (const float*)d_in[44];
  const float* lsig  = (const float*)d_in[45];
  const float* crw   = (const float*)d_in[46];
  const float* crb   = (const float*)d_in[47];
  float* ws  = (float*)d_ws;
  float* out = (float*)d_out;

  k_ac_1 <<<dim3(998),  dim3(256), 0, stream>>>(x, c1w, c1b, xg, s1alw, s1alb, s1arw,
                                                s1blw, s1brw, stt, fc2w, fc2b, fc3w, fc3b, ws);
  k_ac_2 <<<dim3(628),  dim3(256), 0, stream>>>(c2w, c2b, s1blb, g2w, ws);
  k_ac_3 <<<dim3(36),   dim3(256), 0, stream>>>(c3w, c3b, g2as, g2ad, g2b, ws);
  k_ac_4 <<<dim3(6500), dim3(256), 0, stream>>>(fc0w, s3alw, s3arw, ws);
  k_ac_5 <<<dim3(600),  dim3(256), 0, stream>>>(fc1w, fc1b, fc0b, s3alb, s3blw, s3brw, ws);
  k_ac_6 <<<dim3(500),  dim3(256), 0, stream>>>(s3blb, g4w, ws);
  k_ac_7 <<<dim3(500),  dim3(256), 0, stream>>>(g4as, g4ad, g4b, gcnw, ws);
  k_ac_head<<<dim3(1),  dim3(256), 0, stream>>>(gcnb, fcgw, fcgb, fc4w, fc4b,
                                                muw, mub, lsig, crw, crb, ws, out);
}

// Round 10
// 290.801 us; speedup vs baseline: 8.0761x; 1.4234x over previous
//
#include <hip/hip_runtime.h>
#include <math.h>

#define DEV __device__ __forceinline__

// ---------------- graph constants ----------------
constexpr int ESRC[36] = {0,1,2,3,4,5,6,7,8,9,10,11,12,13,14,15,16,17,18,1,2,3,4,5,6,7,8,9,10,11,12,13,14,15,16,17};
constexpr int EDST[36] = {1,2,3,4,5,6,7,8,9,10,11,12,13,14,15,16,17,18,17,0,1,2,3,4,5,6,7,8,9,10,11,12,13,14,15,16};
constexpr int SSRC[55] = {0,1,2,3,4,5,6,7,8,9,10,11,12,13,14,15,16,17,18,1,2,3,4,5,6,7,8,9,10,11,12,13,14,15,16,17,
                          0,1,2,3,4,5,6,7,8,9,10,11,12,13,14,15,16,17,18};
constexpr int SDST[55] = {1,2,3,4,5,6,7,8,9,10,11,12,13,14,15,16,17,18,17,0,1,2,3,4,5,6,7,8,9,10,11,12,13,14,15,16,
                          0,1,2,3,4,5,6,7,8,9,10,11,12,13,14,15,16,17,18};
constexpr float DINV[19] = {0.5773502691896258f,0.5f,0.5f,0.5f,0.5f,0.5f,0.5f,0.5f,0.5f,0.5f,
                            0.5f,0.5f,0.5f,0.5f,0.5f,0.5f,0.5f,0.5f,0.5773502691896258f};

// ---------------- workspace layout (float offsets) ----------------
constexpr int WS_C1  = 0;        // 32*63*63 = 127008 (dead after K2)
constexpr int WS_C2  = 127008;   // 32*30*30 = 28800
constexpr int WS_V   = 155808;   // 6272
constexpr int WS_FC0 = 162080;   // 6000 (fc0 partial q0; NO bias)
constexpr int WS_N1  = 168080;   // 100
constexpr int WS_N2  = 168180;   // 100
constexpr int WS_FC0B= 206280;   // 6000 (fc0 partial q1)
constexpr int WS_PB  = 264384;   // 76000 partials ping (sage1b->gat2mm; sage3a->sage3b; gcn->fcg)
constexpr int WS_PC  = 340384;   // 76000 partials pong (sage3b->gat4mm)
constexpr int WS_FC0C= 416384;   // 6000
constexpr int WS_FC0D= 422384;   // 6000
constexpr int WS_PH2 = 428384;   // 76000 gat mm partials (gat2mm / gat4mm) end 504384
constexpr int WS_N3  = 504384;   // 100
constexpr int WS_FEAT= 504584;   // 200

DEV float wredsum(float v){
  #pragma unroll
  for (int o = 32; o; o >>= 1) v += __shfl_xor(v, o);
  return v;
}
DEV float d4(float4 a, float4 b){ return a.x*b.x + a.y*b.y + a.z*b.z + a.w*b.w; }

// ============================================================================
// SAGE split matmul MODE 2 (verified): h = relu(sum of 4 partials + bias)
// ============================================================================
DEV void sage_split2(int blk, int tid, float* sm,
                     const float* pin, const float* pbias,
                     const float* lw, const float* rw, float* pout)
{
  const int cg_ = blk >> 2, kq = blk & 3;
  const int kb = kq*256;
  const int cntf = (kq < 3) ? 256 : 232;
  const int cnt4 = cntf >> 2;
  float* hS = sm;            // [19][256]
  float* aS = sm + 19*256;   // [19][256]
  for (int c = tid; c < 19*256; c += 256){
    const int n = c >> 8, j = c & 255;
    if (j < cntf){
      const int i = kb + j;
      const float v = pin[n*1000+i] + pin[(19+n)*1000+i] + pin[(38+n)*1000+i]
                    + pin[(57+n)*1000+i] + pbias[i];
      hS[c] = fmaxf(v, 0.f);
    }
  }
  __syncthreads();
  if (tid < cntf){
    float hv[19];
    #pragma unroll
    for (int n=0;n<19;++n) hv[n] = hS[n*256 + tid];
    float ag[19];
    #pragma unroll
    for (int n=0;n<19;++n) ag[n] = 0.f;
    #pragma unroll
    for (int e=0;e<36;++e) ag[EDST[e]] += hv[ESRC[e]];
    #pragma unroll
    for (int n=0;n<19;++n) aS[n*256 + tid] = ag[n];
  }
  __syncthreads();
  const int lane = tid & 63, wv = tid >> 6;
  const int i0 = cg_*8 + 2*wv, i1 = i0 + 1;
  float acc0[19], acc1[19];
  #pragma unroll
  for (int n=0;n<19;++n){ acc0[n]=0.f; acc1[n]=0.f; }
  if (lane < cnt4){
    const float4 wl0 = *((const float4*)(lw + i0*1000) + kq*64 + lane);
    const float4 wl1 = *((const float4*)(lw + i1*1000) + kq*64 + lane);
    const float4 wr0 = *((const float4*)(rw + i0*1000) + kq*64 + lane);
    const float4 wr1 = *((const float4*)(rw + i1*1000) + kq*64 + lane);
    const float4* h4 = (const float4*)hS;
    const float4* a4 = (const float4*)aS;
    #pragma unroll
    for (int n=0;n<19;++n){
      const float4 hv = h4[n*64+lane], av = a4[n*64+lane];
      acc0[n] = d4(wl0,av) + d4(wr0,hv);
      acc1[n] = d4(wl1,av) + d4(wr1,hv);
    }
  }
  #pragma unroll
  for (int n=0;n<19;++n){ acc0[n]=wredsum(acc0[n]); acc1[n]=wredsum(acc1[n]); }
  if (lane == 0){
    #pragma unroll
    for (int n=0;n<19;++n){
      pout[(kq*19+n)*1000 + i0] = acc0[n];
      pout[(kq*19+n)*1000 + i1] = acc1[n];
    }
  }
}

// ============================================================================
// sage1b with INLINE sage1a (verified R8)
// ============================================================================
DEV void sage1b_fused(int blk, int tid, float* sm, const float* xg,
                      const float* alw, const float* alb, const float* arw,
                      const float* lw, const float* rw, float* pout)
{
  const int cg_ = blk >> 2, kq = blk & 3;
  const int kb = kq*256;
  const int cntf = (kq < 3) ? 256 : 232;
  const int cnt4 = cntf >> 2;
  float* hS = sm;
  float* aS = sm + 19*256;
  float xv[19];
  #pragma unroll
  for (int n=0;n<19;++n) xv[n] = xg[n];
  float ag0[19];
  #pragma unroll
  for (int n=0;n<19;++n) ag0[n] = 0.f;
  #pragma unroll
  for (int e=0;e<36;++e) ag0[EDST[e]] += xv[ESRC[e]];
  if (tid < cntf){
    const int i = kb + tid;
    const float a = alw[i], bb = alb[i], r = arw[i];
    float hv[19];
    #pragma unroll
    for (int n=0;n<19;++n){ hv[n] = fmaxf(a*ag0[n] + bb + r*xv[n], 0.f); hS[n*256+tid] = hv[n]; }
    float ag[19];
    #pragma unroll
    for (int n=0;n<19;++n) ag[n] = 0.f;
    #pragma unroll
    for (int e=0;e<36;++e) ag[EDST[e]] += hv[ESRC[e]];
    #pragma unroll
    for (int n=0;n<19;++n) aS[n*256+tid] = ag[n];
  }
  __syncthreads();
  const int lane = tid & 63, wv = tid >> 6;
  const int i0 = cg_*8 + 2*wv, i1 = i0 + 1;
  float acc0[19], acc1[19];
  #pragma unroll
  for (int n=0;n<19;++n){ acc0[n]=0.f; acc1[n]=0.f; }
  if (lane < cnt4){
    const float4 wl0 = *((const float4*)(lw + i0*1000) + kq*64 + lane);
    const float4 wl1 = *((const float4*)(lw + i1*1000) + kq*64 + lane);
    const float4 wr0 = *((const float4*)(rw + i0*1000) + kq*64 + lane);
    const float4 wr1 = *((const float4*)(rw + i1*1000) + kq*64 + lane);
    const float4* h4 = (const float4*)hS;
    const float4* a4 = (const float4*)aS;
    #pragma unroll
    for (int n=0;n<19;++n){
      const float4 hv = h4[n*64+lane], av = a4[n*64+lane];
      acc0[n] = d4(wl0,av) + d4(wr0,hv);
      acc1[n] = d4(wl1,av) + d4(wr1,hv);
    }
  }
  #pragma unroll
  for (int n=0;n<19;++n){ acc0[n]=wredsum(acc0[n]); acc1[n]=wredsum(acc1[n]); }
  if (lane == 0){
    #pragma unroll
    for (int n=0;n<19;++n){
      pout[(kq*19+n)*1000 + i0] = acc0[n];
      pout[(kq*19+n)*1000 + i1] = acc1[n];
    }
  }
}

// ============================================================================
// GAT matmul MODE 2 (verified): h = relu(4 sage partials + bias); W·h
// ============================================================================
DEV void gatmat_split2(int blk, int tid, float* sm,
                       const float* pin, const float* pbias,
                       const float* W, float* pout)
{
  const int cg_ = blk >> 2, kq = blk & 3;
  const int kb = kq*256;
  const int cntf = (kq < 3) ? 256 : 232;
  const int cnt4 = cntf >> 2;
  float* hS = sm;
  for (int c = tid; c < 19*256; c += 256){
    const int n = c >> 8, j = c & 255;
    if (j < cntf){
      const int i = kb + j;
      const float v = pin[n*1000+i] + pin[(19+n)*1000+i] + pin[(38+n)*1000+i]
                    + pin[(57+n)*1000+i] + pbias[i];
      hS[c] = fmaxf(v, 0.f);
    }
  }
  __syncthreads();
  const int lane = tid & 63, wv = tid >> 6;
  const int i0 = cg_*8 + 2*wv, i1 = i0 + 1;
  float acc0[19], acc1[19];
  #pragma unroll
  for (int n=0;n<19;++n){ acc0[n]=0.f; acc1[n]=0.f; }
  if (lane < cnt4){
    const float4 w0 = *((const float4*)(W + i0*1000) + kq*64 + lane);
    const float4 w1 = *((const float4*)(W + i1*1000) + kq*64 + lane);
    const float4* h4 = (const float4*)hS;
    #pragma unroll
    for (int n=0;n<19;++n){
      const float4 hv = h4[n*64+lane];
      acc0[n] = d4(w0,hv);
      acc1[n] = d4(w1,hv);
    }
  }
  #pragma unroll
  for (int n=0;n<19;++n){ acc0[n]=wredsum(acc0[n]); acc1[n]=wredsum(acc1[n]); }
  if (lane == 0){
    #pragma unroll
    for (int n=0;n<19;++n){
      pout[(kq*19+n)*1000 + i0] = acc0[n];
      pout[(kq*19+n)*1000 + i1] = acc1[n];
    }
  }
}

// ---- alpha into sm[320..374] (redundant per block, deterministic; verified R8) ----
DEV void alpha_sm(int t, float* sm, const float* ph, const float* as_,
                  const float* ad_)
{
  const int lane = t & 63, wv = t >> 6;
  float es[19], ed[19];
  #pragma unroll
  for (int n=0;n<19;++n){ es[n]=0.f; ed[n]=0.f; }
  for (int k = t; k < 1000; k += 256){
    const float asv = as_[k], adv = ad_[k];
    #pragma unroll
    for (int n=0;n<19;++n){
      const float hh = ph[n*1000+k] + ph[(19+n)*1000+k] + ph[(38+n)*1000+k] + ph[(57+n)*1000+k];
      es[n] += hh*asv; ed[n] += hh*adv;
    }
  }
  #pragma unroll
  for (int n=0;n<19;++n){ es[n]=wredsum(es[n]); ed[n]=wredsum(ed[n]); }
  if (lane == 0){
    #pragma unroll
    for (int n=0;n<19;++n){ sm[wv*38+n]=es[n]; sm[wv*38+19+n]=ed[n]; }
  }
  __syncthreads();
  if (t < 38) sm[152+t] = sm[t] + sm[38+t] + sm[76+t] + sm[114+t];
  __syncthreads();
  if (t < 55){
    float e = sm[152+SSRC[t]] + sm[171+SDST[t]];
    sm[200+t] = e > 0.f ? e : 0.2f*e;
  }
  __syncthreads();
  if (t < 19){
    float m = -1e30f;
    #pragma unroll
    for (int e=0;e<55;++e) if (SDST[e]==t) m = fmaxf(m, sm[200+e]);
    float den = 0.f;
    #pragma unroll
    for (int e=0;e<55;++e) if (SDST[e]==t) den += expf(sm[200+e]-m);
    sm[260+t]=m; sm[280+t]=den;
  }
  __syncthreads();
  if (t < 55) sm[320+t] = expf(sm[200+t]-sm[260+SDST[t]]) / sm[280+SDST[t]];
  __syncthreads();
}

// ---- sage3a with INLINE gat2 finisher (alpha + h2 reconstruction) ----
DEV void sage3a_fused(int blk, int t, float* sm, const float* ph,
                      const float* as_, const float* ad_, const float* bias,
                      const float* lw, const float* rw, float* pout)
{
  alpha_sm(t, sm, ph, as_, ad_);          // sm[320..374]
  const int cg_ = blk >> 2, kq = blk & 3;
  const int kb = kq*256;
  const int cntf = (kq < 3) ? 256 : 232;
  const int cnt4 = cntf >> 2;
  float* hS = sm + 384;                    // [19][256]
  float* aS = sm + 384 + 4864;             // [19][256]
  if (t < cntf){
    const int i = kb + t;
    float hin[19];
    #pragma unroll
    for (int n=0;n<19;++n)
      hin[n] = ph[n*1000+i] + ph[(19+n)*1000+i] + ph[(38+n)*1000+i] + ph[(57+n)*1000+i];
    float acc[19];
    #pragma unroll
    for (int n=0;n<19;++n) acc[n]=0.f;
    #pragma unroll
    for (int e=0;e<55;++e) acc[SDST[e]] += sm[320+e]*hin[SSRC[e]];
    const float bi = bias[i];
    float hv[19];
    #pragma unroll
    for (int n=0;n<19;++n){ hv[n] = fmaxf(acc[n]+bi, 0.f); hS[n*256+t] = hv[n]; }
    float ag[19];
    #pragma unroll
    for (int n=0;n<19;++n) ag[n]=0.f;
    #pragma unroll
    for (int e=0;e<36;++e) ag[EDST[e]] += hv[ESRC[e]];
    #pragma unroll
    for (int n=0;n<19;++n) aS[n*256+t] = ag[n];
  }
  __syncthreads();
  const int lane = t & 63, wv = t >> 6;
  const int i0 = cg_*8 + 2*wv, i1 = i0 + 1;
  float acc0[19], acc1[19];
  #pragma unroll
  for (int n=0;n<19;++n){ acc0[n]=0.f; acc1[n]=0.f; }
  if (lane < cnt4){
    const float4 wl0 = *((const float4*)(lw + i0*1000) + kq*64 + lane);
    const float4 wl1 = *((const float4*)(lw + i1*1000) + kq*64 + lane);
    const float4 wr0 = *((const float4*)(rw + i0*1000) + kq*64 + lane);
    const float4 wr1 = *((const float4*)(rw + i1*1000) + kq*64 + lane);
    const float4* h4 = (const float4*)hS;
    const float4* a4 = (const float4*)aS;
    #pragma unroll
    for (int n=0;n<19;++n){
      const float4 hv = h4[n*64+lane], av = a4[n*64+lane];
      acc0[n] = d4(wl0,av) + d4(wr0,hv);
      acc1[n] = d4(wl1,av) + d4(wr1,hv);
    }
  }
  #pragma unroll
  for (int n=0;n<19;++n){ acc0[n]=wredsum(acc0[n]); acc1[n]=wredsum(acc1[n]); }
  if (lane == 0){
    #pragma unroll
    for (int n=0;n<19;++n){
      pout[(kq*19+n)*1000 + i0] = acc0[n];
      pout[(kq*19+n)*1000 + i1] = acc1[n];
    }
  }
}

// ---- gcn matmul with INLINE gat4 finisher (verified R8) ----
DEV void gcn_fused_task(int blk, int t, float* sm, const float* ph,
                        const float* as_, const float* ad_, const float* bias,
                        const float* W, float* pout)
{
  alpha_sm(t, sm, ph, as_, ad_);
  const int cg_ = blk >> 2, kq = blk & 3;
  const int kb = kq*256;
  const int cntf = (kq < 3) ? 256 : 232;
  const int cnt4 = cntf >> 2;
  float* hS = sm + 384;
  if (t < cntf){
    const int i = kb + t;
    float hv[19];
    #pragma unroll
    for (int n=0;n<19;++n)
      hv[n] = ph[n*1000+i] + ph[(19+n)*1000+i] + ph[(38+n)*1000+i] + ph[(57+n)*1000+i];
    float acc[19];
    #pragma unroll
    for (int n=0;n<19;++n) acc[n]=0.f;
    #pragma unroll
    for (int e=0;e<55;++e) acc[SDST[e]] += sm[320+e]*hv[SSRC[e]];
    const float bi = bias[i];
    #pragma unroll
    for (int n=0;n<19;++n) hS[n*256+t] = fmaxf(acc[n]+bi, 0.f);
  }
  __syncthreads();
  const int lane = t & 63, wv = t >> 6;
  const int i0 = cg_*8 + 2*wv, i1 = i0 + 1;
  float acc0[19], acc1[19];
  #pragma unroll
  for (int n=0;n<19;++n){ acc0[n]=0.f; acc1[n]=0.f; }
  if (lane < cnt4){
    const float4 w0 = *((const float4*)(W + i0*1000) + kq*64 + lane);
    const float4 w1 = *((const float4*)(W + i1*1000) + kq*64 + lane);
    const float4* h4 = (const float4*)hS;
    #pragma unroll
    for (int n=0;n<19;++n){
      const float4 hv = h4[n*64+lane];
      acc0[n] = d4(w0,hv);
      acc1[n] = d4(w1,hv);
    }
  }
  #pragma unroll
  for (int n=0;n<19;++n){ acc0[n]=wredsum(acc0[n]); acc1[n]=wredsum(acc1[n]); }
  if (lane == 0){
    #pragma unroll
    for (int n=0;n<19;++n){
      pout[(kq*19+n)*1000 + i0] = acc0[n];
      pout[(kq*19+n)*1000 + i1] = acc1[n];
    }
  }
}

// ---- conv tasks (verified R5) ----
DEV void conv1_task(int task, int t, const float* x, const float* c1w,
                    const float* c1b, float* ws)
{
  const int idx = task*256 + t;
  if (idx < 127008){
    const int oc = idx/3969, r = idx - oc*3969, oy = r/63, ox = r - oy*63;
    const float* wp = c1w + oc*25;
    float acc = c1b[oc];
    #pragma unroll
    for (int ky=0;ky<5;++ky){
      const int iy = oy*2 - 1 + ky;
      if ((unsigned)iy < 128u){
        #pragma unroll
        for (int kx=0;kx<5;++kx){
          const int ix = ox*2 - 1 + kx;
          if ((unsigned)ix < 128u) acc += x[iy*128+ix]*wp[ky*5+kx];
        }
      }
    }
    ws[WS_C1+idx] = fmaxf(acc, 0.f);
  }
}

DEV void conv2_task(int task, int t, float* sm, const float* c2w,
                    const float* c2b, float* ws)
{
  const int oc = task >> 2, q = task & 3;
  const int r0 = q*16;
  const int nout = (q < 3) ? 240 : 180;
  float* buf0 = sm; float* buf1 = sm + 4788;
  float rv[19];
  #pragma unroll
  for (int u=0; u<19; ++u){
    const int c = t + u*256; float v = 0.f;
    if (c < 4788){
      const int p = c/1197, r = c - p*1197, lr = r/63, xx = r - lr*63;
      const int iy = r0 + lr;
      if (iy < 63) v = ws[WS_C1 + p*3969 + iy*63 + xx];
    }
    rv[u] = v;
  }
  #pragma unroll
  for (int u=0; u<19; ++u){ const int c = t+u*256; if (c<4788) buf0[c]=rv[u]; }
  __syncthreads();
  const int oy_l = t/30, ox = t - oy_l*30;
  float acc = (t < nout) ? c2b[oc] : 0.f;
  for (int g=0; g<8; ++g){
    float* cur = (g&1) ? buf1 : buf0;
    if (g < 7){
      #pragma unroll
      for (int u=0; u<19; ++u){
        const int c = t + u*256; float v = 0.f;
        if (c < 4788){
          const int p = c/1197, r = c - p*1197, lr = r/63, xx = r - lr*63;
          const int iy = r0 + lr;
          if (iy < 63) v = ws[WS_C1 + (4*(g+1)+p)*3969 + iy*63 + xx];
        }
        rv[u] = v;
      }
    }
    if (t < nout){
      #pragma unroll
      for (int p=0;p<4;++p){
        const float* wp = c2w + (oc*32 + 4*g + p)*25;
        const float* ip = cur + p*1197 + (2*oy_l)*63 + 2*ox;
        #pragma unroll
        for (int ky=0;ky<5;++ky)
          #pragma unroll
          for (int kx=0;kx<5;++kx)
            acc += ip[ky*63+kx]*wp[ky*5+kx];
      }
    }
    if (g < 7){
      __syncthreads();
      float* nxt = (g&1) ? buf0 : buf1;
      #pragma unroll
      for (int u=0; u<19; ++u){ const int c = t+u*256; if (c<4788) nxt[c]=rv[u]; }
      __syncthreads();
    }
  }
  if (t < nout){
    const int oy = q*8 + oy_l;
    ws[WS_C2 + oc*900 + oy*30 + ox] = fmaxf(acc, 0.f);
  }
}

DEV void conv3_task(int oc, int t, float* sm, const float* c3w,
                    const float* c3b, float* ws)
{
  float* buf0 = sm; float* buf1 = sm + 3600;
  float rv[15];
  #pragma unroll
  for (int u=0; u<15; ++u){
    const int c = t + u*256;
    rv[u] = (c < 3600) ? ws[WS_C2 + c] : 0.f;
  }
  #pragma unroll
  for (int u=0; u<15; ++u){ const int c = t+u*256; if (c<3600) buf0[c]=rv[u]; }
  __syncthreads();
  const int oy = t/14, ox = t - oy*14;
  float acc = (t < 196) ? c3b[oc] : 0.f;
  for (int g=0; g<8; ++g){
    float* cur = (g&1) ? buf1 : buf0;
    if (g < 7){
      #pragma unroll
      for (int u=0; u<15; ++u){
        const int c = t + u*256;
        rv[u] = (c < 3600) ? ws[WS_C2 + (g+1)*3600 + c] : 0.f;
      }
    }
    if (t < 196){
      #pragma unroll
      for (int p=0;p<4;++p){
        const float* wp = c3w + (oc*32 + 4*g + p)*25;
        const float* ip = cur + p*900;
        #pragma unroll
        for (int ky=0;ky<5;++ky){
          const int iy = oy*2 - 1 + ky;
          if ((unsigned)iy < 30u){
            #pragma unroll
            for (int kx=0;kx<5;++kx){
              const int ix = ox*2 - 1 + kx;
              if ((unsigned)ix < 30u) acc += ip[iy*30+ix]*wp[ky*5+kx];
            }
          }
        }
      }
    }
    if (g < 7){
      __syncthreads();
      float* nxt = (g&1) ? buf0 : buf1;
      #pragma unroll
      for (int u=0; u<15; ++u){ const int c = t+u*256; if (c<3600) nxt[c]=rv[u]; }
      __syncthreads();
    }
  }
  if (t < 196) ws[WS_V + oc*196 + t] = acc;  // no relu on conv3
}

// ---- fc0 task (verified R5) ----
DEV void fc0_task(int task, int t, const float* fc0w, float* ws)
{
  const int lane = t & 63, wv = t >> 6;
  const int rq = task >> 2, q = task & 3;
  const int row = rq*4 + wv;
  const float4* vr = (const float4*)(ws + WS_V) + q*392;
  const float4* wr = (const float4*)(fc0w) + (size_t)row*1568 + q*392;
  float4 wreg[6];
  #pragma unroll
  for (int u=0; u<6; ++u) wreg[u] = wr[u*64 + lane];
  float4 wtail;
  if (lane < 8) wtail = wr[384 + lane];
  float acc = 0.f;
  #pragma unroll
  for (int u=0; u<6; ++u) acc += d4(wreg[u], vr[u*64 + lane]);
  if (lane < 8) acc += d4(wtail, vr[384 + lane]);
  acc = wredsum(acc);
  if (lane == 0){
    float* pout = ws + (q==0 ? WS_FC0 : q==1 ? WS_FC0B : q==2 ? WS_FC0C : WS_FC0D);
    pout[row] = acc;   // bias added in fc1 consumer
  }
}

// =================== K1: conv1(497) + sage1b-fused(500) + state MLP(1) ===================
__global__ __launch_bounds__(256) void k_ac_1(
    const float* __restrict__ x, const float* __restrict__ c1w, const float* __restrict__ c1b,
    const float* __restrict__ xg,
    const float* __restrict__ s1alw, const float* __restrict__ s1alb, const float* __restrict__ s1arw,
    const float* __restrict__ s1blw, const float* __restrict__ s1brw,
    const float* __restrict__ stt, const float* __restrict__ fc2w, const float* __restrict__ fc2b,
    const float* __restrict__ fc3w, const float* __restrict__ fc3b,
    float* __restrict__ ws)
{
  __shared__ __align__(16) float sm[9728];
  const int b = blockIdx.x, t = threadIdx.x;
  if (b < 497){
    conv1_task(b, t, x, c1w, c1b, ws);
  } else if (b < 997){
    sage1b_fused(b-497, t, sm, xg, s1alw, s1alb, s1arw, s1blw, s1brw, ws+WS_PB);
  } else {
    if (t < 100){
      float acc = fc2b[t];
      #pragma unroll
      for (int k=0;k<20;++k) acc += fc2w[t*20+k]*stt[k];
      sm[t] = acc;
    }
    __syncthreads();
    if (t < 100){
      float acc = fc3b[t];
      for (int k=0;k<100;++k) acc += fc3w[t*100+k]*sm[k];
      ws[WS_N2+t] = acc;
    }
  }
}

// =================== K2: conv2(128) + gat2mm(500) ===================
__global__ __launch_bounds__(256) void k_ac_2(
    const float* __restrict__ c2w, const float* __restrict__ c2b,
    const float* __restrict__ s1blb, const float* __restrict__ g2w,
    float* __restrict__ ws)
{
  __shared__ __align__(16) float sm[9728];
  const int b = blockIdx.x, t = threadIdx.x;
  if (b < 128) conv2_task(b, t, sm, c2w, c2b, ws);
  else gatmat_split2(b-128, t, sm, ws+WS_PB, s1blb, g2w, ws+WS_PH2);
}

// =================== K3: conv3(32) + sage3a-fused(500, inline gat2fin) ===================
__global__ __launch_bounds__(256) void k_ac_3(
    const float* __restrict__ c3w, const float* __restrict__ c3b,
    const float* __restrict__ g2as, const float* __restrict__ g2ad, const float* __restrict__ g2b,
    const float* __restrict__ s3alw, const float* __restrict__ s3arw,
    float* __restrict__ ws)
{
  __shared__ __align__(16) float sm[10112];
  const int b = blockIdx.x, t = threadIdx.x;
  if (b < 32) conv3_task(b, t, sm, c3w, c3b, ws);
  else sage3a_fused(b-32, t, sm, ws+WS_PH2, g2as, g2ad, g2b, s3alw, s3arw, ws+WS_PB);
}

// =================== K4: fc0(6000) + sage3b(500) ===================
__global__ __launch_bounds__(256) void k_ac_4(
    const float* __restrict__ fc0w,
    const float* __restrict__ s3alb, const float* __restrict__ s3blw, const float* __restrict__ s3brw,
    float* __restrict__ ws)
{
  __shared__ __align__(16) float sm[9728];
  const int b = blockIdx.x, t = threadIdx.x;
  if (b < 6000) fc0_task(b, t, fc0w, ws);
  else sage_split2(b-6000, t, sm, ws+WS_PB, s3alb, s3blw, s3brw, ws+WS_PC);
}

// =================== K5: fc1(100) + gat4mm(500) ===================
__global__ __launch_bounds__(256) void k_ac_5(
    const float* __restrict__ fc1w, const float* __restrict__ fc1b,
    const float* __restrict__ fc0b,
    const float* __restrict__ s3blb, const float* __restrict__ g4w,
    float* __restrict__ ws)
{
  __shared__ __align__(16) float sm[4864];
  const int b = blockIdx.x, t = threadIdx.x;
  if (b < 100){
    const int row = b, lane = t & 63, wv = t >> 6;
    const float4* wr = (const float4*)(fc1w + row*6000);
    const float4* p0 = (const float4*)(ws + WS_FC0);
    const float4* p1 = (const float4*)(ws + WS_FC0B);
    const float4* p2 = (const float4*)(ws + WS_FC0C);
    const float4* p3 = (const float4*)(ws + WS_FC0D);
    const float4* bb = (const float4*)fc0b;
    float acc = 0.f;
    #pragma unroll
    for (int u=0; u<6; ++u){
      const int j = t + u*256;
      if (j < 1500){
        const float4 a0=p0[j], a1=p1[j], a2=p2[j], a3=p3[j], bv=bb[j];
        const float4 s = make_float4(a0.x+a1.x+a2.x+a3.x+bv.x, a0.y+a1.y+a2.y+a3.y+bv.y,
                                     a0.z+a1.z+a2.z+a3.z+bv.z, a0.w+a1.w+a2.w+a3.w+bv.w);
        acc += d4(wr[j], s);
      }
    }
    acc = wredsum(acc);
    if (lane == 0) sm[wv] = acc;
    __syncthreads();
    if (t == 0) ws[WS_N1+row] = sm[0]+sm[1]+sm[2]+sm[3] + fc1b[row];
  } else {
    gatmat_split2(b-100, t, sm, ws+WS_PC, s3blb, g4w, ws+WS_PH2);
  }
}

// =================== K6: gcn(500, inline gat4fin) ===================
__global__ __launch_bounds__(256) void k_ac_6(
    const float* __restrict__ g4as, const float* __restrict__ g4ad, const float* __restrict__ g4b,
    const float* __restrict__ gcnw, float* __restrict__ ws)
{
  __shared__ __align__(16) float sm[5248];
  gcn_fused_task(blockIdx.x, threadIdx.x, sm, ws+WS_PH2, g4as, g4ad, g4b, gcnw, ws+WS_PB);
}

// =================== K7: fcg(100, inline gcnfin) ===================
__global__ __launch_bounds__(256) void k_ac_7(
    const float* __restrict__ gcnb, const float* __restrict__ fcgw, const float* __restrict__ fcgb,
    float* __restrict__ ws)
{
  __shared__ float sm[4];
  const int b = blockIdx.x, t = threadIdx.x, lane = t & 63, wv = t >> 6;
  float cc[19];
  #pragma unroll
  for (int m=0;m<19;++m) cc[m] = 2.f*DINV[m]*DINV[m];
  #pragma unroll
  for (int e=0;e<36;++e) cc[ESRC[e]] += DINV[ESRC[e]]*DINV[EDST[e]];
  #pragma unroll
  for (int m=0;m<19;++m) cc[m] *= (1.f/19.f);
  const float* pb = ws + WS_PB;
  const float* wrow = fcgw + b*1000;
  float acc = 0.f;
  #pragma unroll
  for (int u=0; u<4; ++u){
    const int i = t + u*256;
    if (i < 1000){
      float gv = gcnb[i];
      #pragma unroll
      for (int m=0;m<19;++m){
        const float hh = pb[m*1000+i] + pb[(19+m)*1000+i] + pb[(38+m)*1000+i] + pb[(57+m)*1000+i];
        gv += cc[m]*hh;
      }
      acc += wrow[i]*gv;
    }
  }
  acc = wredsum(acc);
  if (lane == 0) sm[wv] = acc;
  __syncthreads();
  if (t == 0) ws[WS_N3+b] = sm[0]+sm[1]+sm[2]+sm[3] + fcgb[b];
}

// =================== K8: fc4(50 blocks x 4 rows, redundant minmax) ===================
__global__ __launch_bounds__(256) void k_ac_8(
    const float* __restrict__ fc4w, const float* __restrict__ fc4b,
    float* __restrict__ ws)
{
  __shared__ __align__(16) float f[300];
  __shared__ float mnmx[6];
  const int b = blockIdx.x, t = threadIdx.x, lane = t & 63, wv = t >> 6;
  for (int c = t; c < 300; c += 256){                       // FIX: loop, 256 thr
    f[c] = (c < 100) ? ws[WS_N1 + c]
         : (c < 200) ? ws[WS_N2 + c - 100]
                     : ws[WS_N3 + c - 200];
  }
  __syncthreads();
  if (wv < 3){
    const int base = wv*100;
    const float v  = f[base + lane];
    const float v2 = (lane < 36) ? f[base + 64 + lane] : v;
    float mn = fminf(v, v2), mx = fmaxf(v, v2);
    #pragma unroll
    for (int o=32;o;o>>=1){ mn = fminf(mn, __shfl_xor(mn,o)); mx = fmaxf(mx, __shfl_xor(mx,o)); }
    if (lane == 0){ mnmx[wv*2]=mn; mnmx[wv*2+1]=mx; }
  }
  __syncthreads();
  for (int c = t; c < 300; c += 256){                       // FIX: loop, 256 thr
    const int g = c/100;
    f[c] = (f[c]-mnmx[g*2])/(mnmx[g*2+1]-mnmx[g*2]);
  }
  __syncthreads();
  const int row = b*4 + wv;
  const float* wp = fc4w + row*300;
  float acc = 0.f;
  #pragma unroll
  for (int it=0; it<5; ++it){
    const int k = it*64 + lane;
    if (k < 300) acc += wp[k]*f[k];
  }
  acc = wredsum(acc);
  if (lane == 0) ws[WS_FEAT+row] = acc + fc4b[row];
}

// =================== K9: head final (mu/sigma/value, 1 block) ===================
__global__ __launch_bounds__(256) void k_ac_9(
    const float* __restrict__ muw, const float* __restrict__ mub,
    const float* __restrict__ lsig, const float* __restrict__ crw, const float* __restrict__ crb,
    float* __restrict__ ws, float* __restrict__ out)
{
  __shared__ __align__(16) float feats[200];
  const int t = threadIdx.x, lane = t & 63, wv = t >> 6;
  if (t < 200) feats[t] = ws[WS_FEAT + t];
  if (t >= 200 && t < 212) out[t - 188] = expf(lsig[t-200]);   // sigma -> out[12..23]
  __syncthreads();
  #pragma unroll
  for (int rr=0; rr<4; ++rr){
    const int row = wv + rr*4;
    if (row < 12){
      const float* wp = muw + row*200;
      float a = 0.f;
      #pragma unroll
      for (int it=0; it<4; ++it){
        const int k = it*64 + lane;
        if (k < 200) a += wp[k]*feats[k];
      }
      a = wredsum(a);
      if (lane == 0) out[row] = tanhf(a + mub[row]);
    } else if (row == 12){
      float a = 0.f;
      #pragma unroll
      for (int it=0; it<4; ++it){
        const int k = it*64 + lane;
        if (k < 200) a += crw[k]*feats[k];
      }
      a = wredsum(a);
      if (lane == 0) out[24] = a + crb[0];
    }
  }
}

extern "C" void kernel_launch(void* const* d_in, const int* in_sizes, int n_in,
                              void* d_out, int out_size, void* d_ws, size_t ws_size,
                              hipStream_t stream)
{
  (void)in_sizes; (void)n_in; (void)out_size; (void)ws_size;
  const float* x     = (const float*)d_in[0];
  const float* stt   = (const float*)d_in[1];
  const float* xg    = (const float*)d_in[2];
  const float* c1w   = (const float*)d_in[3];
  const float* c1b   = (const float*)d_in[4];
  const float* c2w   = (const float*)d_in[5];
  const float* c2b   = (const float*)d_in[6];
  const float* c3w   = (const float*)d_in[7];
  const float* c3b   = (const float*)d_in[8];
  const float* fc0w  = (const float*)d_in[9];
  const float* fc0b  = (const float*)d_in[10];
  const float* fc1w  = (const float*)d_in[11];
  const float* fc1b  = (const float*)d_in[12];
  const float* fc2w  = (const float*)d_in[13];
  const float* fc2b  = (const float*)d_in[14];
  const float* fc3w  = (const float*)d_in[15];
  const float* fc3b  = (const float*)d_in[16];
  const float* s1alw = (const float*)d_in[17];
  const float* s1alb = (const float*)d_in[18];
  const float* s1arw = (const float*)d_in[19];
  const float* s1blw = (const float*)d_in[20];
  const float* s1blb = (const float*)d_in[21];
  const float* s1brw = (const float*)d_in[22];
  const float* g2w   = (const float*)d_in[23];
  const float* g2as  = (const float*)d_in[24];
  const float* g2ad  = (const float*)d_in[25];
  const float* g2b   = (const float*)d_in[26];
  const float* s3alw = (const float*)d_in[27];
  const float* s3alb = (const float*)d_in[28];
  const float* s3arw = (const float*)d_in[29];
  const float* s3blw = (const float*)d_in[30];
  const float* s3blb = (const float*)d_in[31];
  const float* s3brw = (const float*)d_in[32];
  const float* g4w   = (const float*)d_in[33];
  const float* g4as  = (const float*)d_in[34];
  const float* g4ad  = (const float*)d_in[35];
  const float* g4b   = (const float*)d_in[36];
  const float* gcnw  = (const float*)d_in[37];
  const float* gcnb  = (const float*)d_in[38];
  const float* fcgw  = (const float*)d_in[39];
  const float* fcgb  = (const float*)d_in[40];
  const float* fc4w  = (const float*)d_in[41];
  const float* fc4b  = (const float*)d_in[42];
  const float* muw   = (const float*)d_in[43];
  const float* mub   = (const float*)d_in[44];
  const float* lsig  = (const float*)d_in[45];
  const float* crw   = (const float*)d_in[46];
  const float* crb   = (const float*)d_in[47];
  float* ws  = (float*)d_ws;
  float* out = (float*)d_out;

  k_ac_1 <<<dim3(998),  dim3(256), 0, stream>>>(x, c1w, c1b, xg, s1alw, s1alb, s1arw,
                                                s1blw, s1brw, stt, fc2w, fc2b, fc3w, fc3b, ws);
  k_ac_2 <<<dim3(628),  dim3(256), 0, stream>>>(c2w, c2b, s1blb, g2w, ws);
  k_ac_3 <<<dim3(532),  dim3(256), 0, stream>>>(c3w, c3b, g2as, g2ad, g2b, s3alw, s3arw, ws);
  k_ac_4 <<<dim3(6500), dim3(256), 0, stream>>>(fc0w, s3alb, s3blw, s3brw, ws);
  k_ac_5 <<<dim3(600),  dim3(256), 0, stream>>>(fc1w, fc1b, fc0b, s3blb, g4w, ws);
  k_ac_6 <<<dim3(500),  dim3(256), 0, stream>>>(g4as, g4ad, g4b, gcnw, ws);
  k_ac_7 <<<dim3(100),  dim3(256), 0, stream>>>(gcnb, fcgw, fcgb, ws);
  k_ac_8 <<<dim3(50),   dim3(256), 0, stream>>>(fc4w, fc4b, ws);
  k_ac_9 <<<dim3(1),    dim3(256), 0, stream>>>(muw, mub, lsig, crw, crb, ws, out);
}